// Round 7
// baseline (491.824 us; speedup 1.0000x reference)
//
#include <hip/hip_runtime.h>
#include <hip/hip_cooperative_groups.h>
#include <math.h>

namespace cg = cooperative_groups;

#define B_ 32
#define N_ 1024
#define H_ 768
#define A_ 8
#define TOPK_ 20
#define CH_ 32     // row-chunks per batch (32 rows each) for both att and h phases
#define CMAX_ 1280

__device__ __forceinline__ float wsum(float x) {
#pragma unroll
    for (int off = 32; off > 0; off >>= 1) x += __shfl_xor(x, off);
    return x;
}

// ===========================================================================
// FUSED cooperative kernel: A(ind/topk) -> B(Hyper) -> C(UGpart) -> D0(red)
// -> D1(finalize), separated by grid.sync().  block=256, LDS 32KB.
// ===========================================================================
__global__ __launch_bounds__(256, 4) void fused_all(
    const float* __restrict__ h, const float* __restrict__ att,
    const int* __restrict__ a_idx, const int* __restrict__ b_idx,
    const float* __restrict__ speak_all,
    const float* __restrict__ W_w, const float* __restrict__ W_b,
    const float* __restrict__ S_w, const float* __restrict__ S_b,
    float* __restrict__ out,
    float* __restrict__ aind, float* __restrict__ bind,
    float* __restrict__ Dv, float* __restrict__ De,
    int* __restrict__ npadArr, float4* __restrict__ comp,
    float* __restrict__ Hyper, float* __restrict__ UGpart,
    float* __restrict__ U, float* __restrict__ G)
{
    cg::grid_group grid = cg::this_grid();
    const int bid = blockIdx.x, nb = gridDim.x;
    const int t = threadIdx.x;
    const int w = t >> 6, lane = t & 63;
    __shared__ float S[8192];      // 32 KB, phase-aliased
    __shared__ float sredA[16];
    __shared__ float smz[8];
    __shared__ int   sidxA[4];

    // ---------------- Phase A: indicators, Dv, De, compacted row list ------
    for (int b = bid; b < B_; b += nb) {
        for (int i = t; i < 2 * N_; i += 256) S[i] = 0.f;
        __syncthreads();
        for (int jj = 0; jj < 4; ++jj) {
            const int j = (w << 2) + jj;          // 0..15
            const int which = j >> 3, r = j & 7;
            const int idx = which ? b_idx[b * A_ + r] : a_idx[b * A_ + r];
            if (idx != 0) {                       // mask = (idx != 0)
                const float* row = att + ((size_t)b * N_ + idx) * N_;
                float v[16];
#pragma unroll
                for (int k = 0; k < 16; ++k) v[k] = row[(k << 6) + lane];
                float* dst = S + which * N_;
                for (int tt = 0; tt < TOPK_; ++tt) {
                    float bv = v[0]; int bk = 0;
#pragma unroll
                    for (int k = 1; k < 16; ++k)
                        if (v[k] > bv) { bv = v[k]; bk = k; }   // lower col wins ties
                    int bc = (bk << 6) + lane;
#pragma unroll
                    for (int off = 32; off > 0; off >>= 1) {
                        float ov = __shfl_xor(bv, off);
                        int oc = __shfl_xor(bc, off);
                        if (ov > bv || (ov == bv && oc < bc)) { bv = ov; bc = oc; }
                    }
                    if (lane == 0) dst[bc] = 1.f;   // benign same-value races
                    if (lane == (bc & 63)) v[bc >> 6] = -INFINITY;
                }
            }
        }
        __syncthreads();
        float sum0 = 0.f, sum1 = 0.f, sum2 = 0.f;
        for (int n = t; n < N_; n += 256) {
            const float sa = S[n], sb = S[N_ + n];
            const float ss = speak_all[(size_t)b * 3 * N_ + n];
            aind[b * N_ + n] = sa; bind[b * N_ + n] = sb;
            Dv[b * N_ + n] = 1.f / sqrtf(sa + sb + ss + 1.f);
            sum0 += sa; sum1 += sb; sum2 += ss;
        }
        sum0 = wsum(sum0); sum1 = wsum(sum1); sum2 = wsum(sum2);
        if (lane == 0) { sredA[w*3+0] = sum0; sredA[w*3+1] = sum1; sredA[w*3+2] = sum2; }
        __syncthreads();
        if (t < 3) De[b * 3 + t] = 1.f / sqrtf(sredA[t] + sredA[3+t] + sredA[6+t] + sredA[9+t]);
        if (w == 0) {   // wave-0 serial compaction, 16 chunks of 64
            int off = 0;
            for (int k = 0; k < 16; ++k) {
                const int n = (k << 6) + lane;
                const float sa = S[n], sb = S[N_ + n];
                const float ss = speak_all[(size_t)b * 3 * N_ + n];
                const bool act = (sa + sb + ss) > 0.f;
                const unsigned long long m = __ballot(act);
                const int rank = (int)__popcll(m & ((1ull << lane) - 1ull));
                if (act) comp[(size_t)b * CMAX_ + off + rank] =
                             make_float4(__int_as_float(n), sa, sb, ss);
                off += (int)__popcll(m);
            }
            const int npad = (off + 255) & ~255;
            for (int i = off + lane; i < npad; i += 64)
                comp[(size_t)b * CMAX_ + i] = make_float4(__int_as_float(0), 0.f, 0.f, 0.f);
            if (lane == 0) npadArr[b] = npad;
        }
        __syncthreads();
    }
    __threadfence();
    grid.sync();

    // ---------------- Phase B: Hyper = Hyper0 @ att ------------------------
    for (int wk = bid; wk < B_ * 32; wk += nb) {
        const int b = wk >> 5, chunk = wk & 31;
        const int npad = npadArr[b];
        float4* scomp = (float4*)S;          // S[0..4095]
        float* scr = S + 4096;               // S[4096..7423], stride-13
        for (int i = t; i < npad; i += 256) scomp[i] = comp[(size_t)b * CMAX_ + i];
        __syncthreads();
        const int cx = t & 7, ig = t >> 3;
        float a0x=0,a0y=0,a0z=0,a0w=0, a1x=0,a1y=0,a1z=0,a1w=0, a2x=0,a2y=0,a2z=0,a2w=0;
        const float* bb = att + (size_t)b * N_ * N_ + chunk * 32 + cx * 4;
#pragma unroll 4
        for (int i = ig; i < npad; i += 32) {
            const float4 c = scomp[i];
            const float4 v = *(const float4*)(bb + (size_t)__float_as_int(c.x) * N_);
            a0x += c.y*v.x; a0y += c.y*v.y; a0z += c.y*v.z; a0w += c.y*v.w;
            a1x += c.z*v.x; a1y += c.z*v.y; a1z += c.z*v.z; a1w += c.z*v.w;
            a2x += c.w*v.x; a2y += c.w*v.y; a2z += c.w*v.z; a2w += c.w*v.w;
        }
        __syncthreads();
        float vals[12] = {a0x,a0y,a0z,a0w, a1x,a1y,a1z,a1w, a2x,a2y,a2z,a2w};
#pragma unroll
        for (int k = 0; k < 12; ++k) scr[t * 13 + k] = vals[k];
        __syncthreads();
        for (int s2 = 16; s2 > 0; s2 >>= 1) {
            if (ig < s2) {
#pragma unroll
                for (int k = 0; k < 12; ++k)
                    scr[t * 13 + k] += scr[(t + s2 * 8) * 13 + k];
            }
            __syncthreads();
        }
        if (ig == 0) {
#pragma unroll
            for (int e = 0; e < 3; ++e)
#pragma unroll
                for (int j = 0; j < 4; ++j)
                    Hyper[(size_t)(b * 3 + e) * N_ + chunk * 32 + cx * 4 + j] =
                        scr[t * 13 + e * 4 + j];
        }
        __syncthreads();
    }
    __threadfence();
    grid.sync();

    // ---------------- Phase C: softmax stats + partial U,G over h ----------
    for (int wk = bid; wk < B_ * CH_; wk += nb) {
        const int b = wk >> 5, c = wk & 31;
        const int n0 = c << 5;
        float* sH = S;              // 3072
        float* sw6 = S + 3072;      // 192
        for (int i = t; i < 768; i += 256)
            ((float4*)sH)[i] = ((const float4*)(Hyper + (size_t)b * 3 * N_))[i];
        __syncthreads();
        if (w < 3) {
            const float* He = sH + w * N_;
            float m = -INFINITY;
            for (int n = lane; n < N_; n += 64) m = fmaxf(m, He[n]);
#pragma unroll
            for (int off = 32; off > 0; off >>= 1) m = fmaxf(m, __shfl_xor(m, off));
            float z = 0.f;
            for (int n = lane; n < N_; n += 64) z += expf(He[n] - m);
            z = wsum(z);
            if (lane == 0) { smz[w] = m; smz[4 + w] = 1.f / z; }
        }
        __syncthreads();
        if (t < 96) {
            const int e = t >> 5, r = t & 31;
            const float Hv = sH[e * N_ + n0 + r];
            sw6[e * 32 + r] = expf(Hv - smz[e]) * smz[4 + e];
            sw6[96 + e * 32 + r] = Hv * Dv[b * N_ + n0 + r];
        }
        __syncthreads();
        if (t < 192) {
            float u0x=0,u0y=0,u0z=0,u0w=0, u1x=0,u1y=0,u1z=0,u1w=0, u2x=0,u2y=0,u2z=0,u2w=0;
            float g0x=0,g0y=0,g0z=0,g0w=0, g1x=0,g1y=0,g1z=0,g1w=0, g2x=0,g2y=0,g2z=0,g2w=0;
            const float* base = h + (size_t)b * N_ * H_ + (size_t)n0 * H_ + t * 4;
#pragma unroll 8
            for (int r = 0; r < 32; ++r) {
                const float4 v = *(const float4*)(base + (size_t)r * H_);
                const float w0 = sw6[r], w1 = sw6[32 + r], w2 = sw6[64 + r];
                const float g0 = sw6[96 + r], g1 = sw6[128 + r], g2 = sw6[160 + r];
                u0x += w0*v.x; u0y += w0*v.y; u0z += w0*v.z; u0w += w0*v.w;
                u1x += w1*v.x; u1y += w1*v.y; u1z += w1*v.z; u1w += w1*v.w;
                u2x += w2*v.x; u2y += w2*v.y; u2z += w2*v.z; u2w += w2*v.w;
                g0x += g0*v.x; g0y += g0*v.y; g0z += g0*v.z; g0w += g0*v.w;
                g1x += g1*v.x; g1y += g1*v.y; g1z += g1*v.z; g1w += g1*v.w;
                g2x += g2*v.x; g2y += g2*v.y; g2z += g2*v.z; g2w += g2*v.w;
            }
            float* up = UGpart + (size_t)(b * CH_ + c) * 6 * H_ + t * 4;
            *(float4*)(up)          = make_float4(u0x, u0y, u0z, u0w);
            *(float4*)(up + H_)     = make_float4(u1x, u1y, u1z, u1w);
            *(float4*)(up + 2*H_)   = make_float4(u2x, u2y, u2z, u2w);
            *(float4*)(up + 3*H_)   = make_float4(g0x, g0y, g0z, g0w);
            *(float4*)(up + 4*H_)   = make_float4(g1x, g1y, g1z, g1w);
            *(float4*)(up + 5*H_)   = make_float4(g2x, g2y, g2z, g2w);
        }
        __syncthreads();
    }
    __threadfence();
    grid.sync();

    // ---------------- Phase D0: reduce partials to U,G ---------------------
    for (int gid = bid * 256 + t; gid < B_ * 1152; gid += nb * 256) {
        const int b = gid / 1152, rem = gid % 1152;
        const int s = rem / 192, col = (rem % 192) * 4;
        const float* p = UGpart + (size_t)b * CH_ * 6 * H_ + s * H_ + col;
        float4 A0 = make_float4(0,0,0,0), A1 = make_float4(0,0,0,0);
        float4 A2 = make_float4(0,0,0,0), A3 = make_float4(0,0,0,0);
#pragma unroll
        for (int c4 = 0; c4 < CH_; c4 += 4) {
            const float4 v0 = *(const float4*)(p + (size_t)(c4 + 0) * 6 * H_);
            const float4 v1 = *(const float4*)(p + (size_t)(c4 + 1) * 6 * H_);
            const float4 v2 = *(const float4*)(p + (size_t)(c4 + 2) * 6 * H_);
            const float4 v3 = *(const float4*)(p + (size_t)(c4 + 3) * 6 * H_);
            A0.x += v0.x; A0.y += v0.y; A0.z += v0.z; A0.w += v0.w;
            A1.x += v1.x; A1.y += v1.y; A1.z += v1.z; A1.w += v1.w;
            A2.x += v2.x; A2.y += v2.y; A2.z += v2.z; A2.w += v2.w;
            A3.x += v3.x; A3.y += v3.y; A3.z += v3.z; A3.w += v3.w;
        }
        const float4 acc = make_float4(A0.x+A1.x+A2.x+A3.x, A0.y+A1.y+A2.y+A3.y,
                                       A0.z+A1.z+A2.z+A3.z, A0.w+A1.w+A2.w+A3.w);
        if (s < 3) *(float4*)(U + ((size_t)(b * 3 + s)) * H_ + col) = acc;
        else       *(float4*)(G + ((size_t)(b * 3 + s - 3)) * H_ + col) = acc;
    }
    __threadfence();
    grid.sync();

    // ---------------- Phase D1: finalize -----------------------------------
    for (int b = bid; b < B_; b += nb) {
        float* sKh = S;              // 2304
        float* sscore = S + 2304;    // 1024
        const float* Ub = U + (size_t)b * 3 * H_;
        const float* Gb = G + (size_t)b * 3 * H_;

        float p0 = 0.f, p1 = 0.f, p2 = 0.f;
        for (int j = t; j < H_; j += 256) {
            const float ww = W_w[j];
            p0 += Ub[j] * ww; p1 += Ub[H_ + j] * ww; p2 += Ub[2 * H_ + j] * ww;
        }
        p0 = wsum(p0); p1 = wsum(p1); p2 = wsum(p2);
        if (lane == 0) { sredA[w*3+0] = p0; sredA[w*3+1] = p1; sredA[w*3+2] = p2; }
        __syncthreads();
        const float wb = W_b[0];
        const float l0 = sredA[0] + sredA[3] + sredA[6] + sredA[9]  + wb;
        const float l1 = sredA[1] + sredA[4] + sredA[7] + sredA[10] + wb;
        const float l2 = sredA[2] + sredA[5] + sredA[8] + sredA[11] + wb;
        const float mx = fmaxf(l0, fmaxf(l1, l2));
        const float e0 = expf(l0 - mx), e1 = expf(l1 - mx), e2 = expf(l2 - mx);
        const float inv = 1.f / (e0 + e1 + e2);
        const float wd0 = e0 * inv * De[b * 3 + 0];
        const float wd1 = e1 * inv * De[b * 3 + 1];
        const float wd2 = e2 * inv * De[b * 3 + 2];
        __syncthreads();

        for (int j = t; j < H_; j += 256) {
            sKh[j]          = wd0 * Gb[j];
            sKh[H_ + j]     = wd1 * Gb[H_ + j];
            sKh[2 * H_ + j] = wd2 * Gb[2 * H_ + j];
        }
        __syncthreads();

        float q0 = 0.f, q1 = 0.f, q2 = 0.f;
        for (int j = t; j < H_; j += 256) {
            const float sw2 = S_w[j];
            q0 += sKh[j] * sw2; q1 += sKh[H_ + j] * sw2; q2 += sKh[2 * H_ + j] * sw2;
        }
        q0 = wsum(q0); q1 = wsum(q1); q2 = wsum(q2);
        if (lane == 0) { sredA[w*3+0] = q0; sredA[w*3+1] = q1; sredA[w*3+2] = q2; }
        __syncthreads();
        q0 = sredA[0] + sredA[3] + sredA[6] + sredA[9];
        q1 = sredA[1] + sredA[4] + sredA[7] + sredA[10];
        q2 = sredA[2] + sredA[5] + sredA[8] + sredA[11];

        const float sb0 = S_b[0];
        const float* av = aind + b * N_;
        const float* bv2 = bind + b * N_;
        const float* dv = Dv + b * N_;
        const float* sv = speak_all + (size_t)b * 3 * N_;
        for (int n = t; n < N_; n += 256)
            sscore[n] = dv[n] * (av[n] * q0 + bv2[n] * q1 + sv[n] * q2) + sb0;
        __syncthreads();

        int r0;
        {
            float best = -INFINITY; int bi = N_;
            for (int n = t; n < N_; n += 256) {
                const float s = sscore[n];
                if (s > best || (s == best && n < bi)) { best = s; bi = n; }
            }
#pragma unroll
            for (int off = 32; off > 0; off >>= 1) {
                const float ov = __shfl_xor(best, off); const int oi = __shfl_xor(bi, off);
                if (ov > best || (ov == best && oi < bi)) { best = ov; bi = oi; }
            }
            if (lane == 0) { sredA[w] = best; sidxA[w] = bi; }
            __syncthreads();
            float v = -INFINITY; int i = N_;
            for (int k = 0; k < 4; ++k)
                if (sredA[k] > v || (sredA[k] == v && sidxA[k] < i)) { v = sredA[k]; i = sidxA[k]; }
            r0 = i;
        }
        __syncthreads();
        int r1;
        {
            float best = -INFINITY; int bi = N_;
            for (int n = t; n < N_; n += 256) {
                if (n == r0) continue;
                const float s = sscore[n];
                if (s > best || (s == best && n < bi)) { best = s; bi = n; }
            }
#pragma unroll
            for (int off = 32; off > 0; off >>= 1) {
                const float ov = __shfl_xor(best, off); const int oi = __shfl_xor(bi, off);
                if (ov > best || (ov == best && oi < bi)) { best = ov; bi = oi; }
            }
            if (lane == 0) { sredA[w] = best; sidxA[w] = bi; }
            __syncthreads();
            float v = -INFINITY; int i = N_;
            for (int k = 0; k < 4; ++k)
                if (sredA[k] > v || (sredA[k] == v && sidxA[k] < i)) { v = sredA[k]; i = sidxA[k]; }
            r1 = i;
        }

        float* ob = out + (size_t)b * 2 * H_;
        {
            const float d = dv[r0], wa = av[r0], wbn = bv2[r0], wsv = sv[r0];
            for (int j = t; j < H_; j += 256)
                ob[j] = d * (wa * sKh[j] + wbn * sKh[H_ + j] + wsv * sKh[2 * H_ + j]);
        }
        {
            const float d = dv[r1], wa = av[r1], wbn = bv2[r1], wsv = sv[r1];
            for (int j = t; j < H_; j += 256)
                ob[H_ + j] = d * (wa * sKh[j] + wbn * sKh[H_ + j] + wsv * sKh[2 * H_ + j]);
        }
        __syncthreads();
    }
}

// ===========================================================================
// Fallback: round-6 five-kernel chain (used only if cooperative launch fails)
// ===========================================================================
__global__ __launch_bounds__(1024) void k1_ind(
    const float* __restrict__ att, const int* __restrict__ a_idx,
    const int* __restrict__ b_idx, const float* __restrict__ speak_all,
    float* __restrict__ aind, float* __restrict__ bind,
    float* __restrict__ Dv, float* __restrict__ De,
    float4* __restrict__ comp, int* __restrict__ npadArr)
{
    const int b = blockIdx.x;
    const int tid = threadIdx.x;
    const int w = tid >> 6, lane = tid & 63;
    __shared__ float s_ind[2][N_];
    __shared__ float s_red[3][16];
    __shared__ int wcnt[16];
    __shared__ int woff[17];

    s_ind[0][tid] = 0.f;
    s_ind[1][tid] = 0.f;
    __syncthreads();

    const int which = w >> 3;
    const int r = w & 7;
    const int idx = which ? b_idx[b * A_ + r] : a_idx[b * A_ + r];
    if (idx != 0) {
        const float* row = att + ((size_t)b * N_ + idx) * N_;
        float v[16];
#pragma unroll
        for (int k = 0; k < 16; ++k) v[k] = row[(k << 6) + lane];
        float* dst = s_ind[which];
        for (int t2 = 0; t2 < TOPK_; ++t2) {
            float bv = v[0]; int bk = 0;
#pragma unroll
            for (int k = 1; k < 16; ++k)
                if (v[k] > bv) { bv = v[k]; bk = k; }
            int bc = (bk << 6) + lane;
#pragma unroll
            for (int off = 32; off > 0; off >>= 1) {
                float ov = __shfl_xor(bv, off);
                int oc = __shfl_xor(bc, off);
                if (ov > bv || (ov == bv && oc < bc)) { bv = ov; bc = oc; }
            }
            if (lane == 0) dst[bc] = 1.f;
            if (lane == (bc & 63)) v[bc >> 6] = -INFINITY;
        }
    }
    __syncthreads();

    const float sa = s_ind[0][tid], sb = s_ind[1][tid];
    const float ss = speak_all[(size_t)b * 3 * N_ + tid];
    aind[b * N_ + tid] = sa;
    bind[b * N_ + tid] = sb;
    Dv[b * N_ + tid] = 1.f / sqrtf(sa + sb + ss + 1.f);

    float p[3] = {sa, sb, ss};
#pragma unroll
    for (int e = 0; e < 3; ++e) {
        float x = wsum(p[e]);
        if (lane == 0) s_red[e][w] = x;
    }

    const bool act = (sa + sb + ss) > 0.f;
    const unsigned long long m = __ballot(act);
    const int wrank = (int)__popcll(m & ((1ull << lane) - 1ull));
    if (lane == 0) wcnt[w] = (int)__popcll(m);
    __syncthreads();
    if (tid == 0) {
        int s = 0;
        for (int i = 0; i < 16; ++i) { woff[i] = s; s += wcnt[i]; }
        woff[16] = s;
        npadArr[b] = (s + 255) & ~255;
    }
    if (tid < 3) {
        float s = 0.f;
        for (int i = 0; i < 16; ++i) s += s_red[tid][i];
        De[b * 3 + tid] = 1.f / sqrtf(s);
    }
    __syncthreads();
    const int nact = woff[16];
    const int npad = (nact + 255) & ~255;
    if (act)
        comp[(size_t)b * CMAX_ + woff[w] + wrank] = make_float4(__int_as_float(tid), sa, sb, ss);
    for (int i = nact + tid; i < npad; i += 1024)
        comp[(size_t)b * CMAX_ + i] = make_float4(__int_as_float(0), 0.f, 0.f, 0.f);
}

__global__ __launch_bounds__(256, 2) void k2_hyper(
    const float* __restrict__ att, const float4* __restrict__ comp,
    const int* __restrict__ npadArr, float* __restrict__ Hyper)
{
    const int b = blockIdx.y;
    const int col0 = blockIdx.x * 32;
    const int t = threadIdx.x;
    const int cx = t & 7, ig = t >> 3;
    __shared__ float4 scomp[1024];
    __shared__ float scr[256 * 13];

    const int npad = npadArr[b];
    for (int i = t; i < npad; i += 256) scomp[i] = comp[(size_t)b * CMAX_ + i];
    __syncthreads();

    float a0x=0,a0y=0,a0z=0,a0w=0, a1x=0,a1y=0,a1z=0,a1w=0, a2x=0,a2y=0,a2z=0,a2w=0;
    const float* bb = att + (size_t)b * N_ * N_ + col0 + cx * 4;
#pragma unroll 4
    for (int i = ig; i < npad; i += 32) {
        const float4 c = scomp[i];
        const float4 v = *(const float4*)(bb + (size_t)__float_as_int(c.x) * N_);
        a0x += c.y*v.x; a0y += c.y*v.y; a0z += c.y*v.z; a0w += c.y*v.w;
        a1x += c.z*v.x; a1y += c.z*v.y; a1z += c.z*v.z; a1w += c.z*v.w;
        a2x += c.w*v.x; a2y += c.w*v.y; a2z += c.w*v.z; a2w += c.w*v.w;
    }
    __syncthreads();

    float vals[12] = {a0x,a0y,a0z,a0w, a1x,a1y,a1z,a1w, a2x,a2y,a2z,a2w};
#pragma unroll
    for (int k = 0; k < 12; ++k) scr[t * 13 + k] = vals[k];
    __syncthreads();
    for (int s = 16; s > 0; s >>= 1) {
        if (ig < s) {
#pragma unroll
            for (int k = 0; k < 12; ++k)
                scr[t * 13 + k] += scr[(t + s * 8) * 13 + k];
        }
        __syncthreads();
    }
    if (ig == 0) {
#pragma unroll
        for (int e = 0; e < 3; ++e)
#pragma unroll
            for (int j = 0; j < 4; ++j)
                Hyper[(size_t)(b * 3 + e) * N_ + col0 + cx * 4 + j] = scr[t * 13 + e * 4 + j];
    }
}

__global__ __launch_bounds__(192, 2) void k4_ug(
    const float* __restrict__ h, const float* __restrict__ Hyper,
    const float* __restrict__ Dv, float* __restrict__ UGpart)
{
    const int b = blockIdx.y, c = blockIdx.x;
    const int n0 = c * 32;
    const int t = threadIdx.x;
    const int wv = t >> 6, lane = t & 63;
    __shared__ float sH[3 * N_];
    __shared__ float sw6[6][32];
    __shared__ float smz[6];

    for (int i = t; i < 3 * N_ / 4; i += 192)
        ((float4*)sH)[i] = ((const float4*)(Hyper + (size_t)b * 3 * N_))[i];
    __syncthreads();

    {
        const float* He = sH + wv * N_;
        float m = -INFINITY;
        for (int n = lane; n < N_; n += 64) m = fmaxf(m, He[n]);
#pragma unroll
        for (int off = 32; off > 0; off >>= 1) m = fmaxf(m, __shfl_xor(m, off));
        float z = 0.f;
        for (int n = lane; n < N_; n += 64) z += expf(He[n] - m);
        z = wsum(z);
        if (lane == 0) { smz[wv] = m; smz[3 + wv] = 1.f / z; }
    }
    __syncthreads();
    if (t < 96) {
        const int e = t >> 5, r = t & 31;
        const float Hv = sH[e * N_ + n0 + r];
        sw6[e][r] = expf(Hv - smz[e]) * smz[3 + e];
        sw6[3 + e][r] = Hv * Dv[b * N_ + n0 + r];
    }
    __syncthreads();

    float u0x=0,u0y=0,u0z=0,u0w=0, u1x=0,u1y=0,u1z=0,u1w=0, u2x=0,u2y=0,u2z=0,u2w=0;
    float g0x=0,g0y=0,g0z=0,g0w=0, g1x=0,g1y=0,g1z=0,g1w=0, g2x=0,g2y=0,g2z=0,g2w=0;
    const float* base = h + (size_t)b * N_ * H_ + (size_t)n0 * H_ + t * 4;
#pragma unroll 8
    for (int r = 0; r < 32; ++r) {
        const float4 v = *(const float4*)(base + (size_t)r * H_);
        const float w0 = sw6[0][r], w1 = sw6[1][r], w2 = sw6[2][r];
        const float g0 = sw6[3][r], g1 = sw6[4][r], g2 = sw6[5][r];
        u0x += w0*v.x; u0y += w0*v.y; u0z += w0*v.z; u0w += w0*v.w;
        u1x += w1*v.x; u1y += w1*v.y; u1z += w1*v.z; u1w += w1*v.w;
        u2x += w2*v.x; u2y += w2*v.y; u2z += w2*v.z; u2w += w2*v.w;
        g0x += g0*v.x; g0y += g0*v.y; g0z += g0*v.z; g0w += g0*v.w;
        g1x += g1*v.x; g1y += g1*v.y; g1z += g1*v.z; g1w += g1*v.w;
        g2x += g2*v.x; g2y += g2*v.y; g2z += g2*v.z; g2w += g2*v.w;
    }
    float* up = UGpart + (size_t)(b * CH_ + c) * 6 * H_ + t * 4;
    *(float4*)(up)          = make_float4(u0x, u0y, u0z, u0w);
    *(float4*)(up + H_)     = make_float4(u1x, u1y, u1z, u1w);
    *(float4*)(up + 2*H_)   = make_float4(u2x, u2y, u2z, u2w);
    *(float4*)(up + 3*H_)   = make_float4(g0x, g0y, g0z, g0w);
    *(float4*)(up + 4*H_)   = make_float4(g1x, g1y, g1z, g1w);
    *(float4*)(up + 5*H_)   = make_float4(g2x, g2y, g2z, g2w);
}

__global__ __launch_bounds__(256, 2) void k4b_red(
    const float* __restrict__ UGpart, float* __restrict__ U, float* __restrict__ G)
{
    const int gid = blockIdx.x * 256 + threadIdx.x;
    const int b = gid / 1152;
    const int rem = gid % 1152;
    const int s = rem / 192;
    const int col = (rem % 192) * 4;

    const float* p = UGpart + (size_t)b * CH_ * 6 * H_ + s * H_ + col;
    float4 a0 = make_float4(0,0,0,0), a1 = make_float4(0,0,0,0);
    float4 a2 = make_float4(0,0,0,0), a3 = make_float4(0,0,0,0);
#pragma unroll
    for (int c = 0; c < CH_; c += 4) {
        const float4 v0 = *(const float4*)(p + (size_t)(c + 0) * 6 * H_);
        const float4 v1 = *(const float4*)(p + (size_t)(c + 1) * 6 * H_);
        const float4 v2 = *(const float4*)(p + (size_t)(c + 2) * 6 * H_);
        const float4 v3 = *(const float4*)(p + (size_t)(c + 3) * 6 * H_);
        a0.x += v0.x; a0.y += v0.y; a0.z += v0.z; a0.w += v0.w;
        a1.x += v1.x; a1.y += v1.y; a1.z += v1.z; a1.w += v1.w;
        a2.x += v2.x; a2.y += v2.y; a2.z += v2.z; a2.w += v2.w;
        a3.x += v3.x; a3.y += v3.y; a3.z += v3.z; a3.w += v3.w;
    }
    const float4 acc = make_float4(a0.x+a1.x+a2.x+a3.x, a0.y+a1.y+a2.y+a3.y,
                                   a0.z+a1.z+a2.z+a3.z, a0.w+a1.w+a2.w+a3.w);
    if (s < 3) *(float4*)(U + ((size_t)(b * 3 + s)) * H_ + col) = acc;
    else       *(float4*)(G + ((size_t)(b * 3 + s - 3)) * H_ + col) = acc;
}

__global__ __launch_bounds__(256) void k5_fin(
    const float* __restrict__ U, const float* __restrict__ G,
    const float* __restrict__ De, const float* __restrict__ Dv,
    const float* __restrict__ aind, const float* __restrict__ bind,
    const float* __restrict__ speak_all,
    const float* __restrict__ W_w, const float* __restrict__ W_b,
    const float* __restrict__ S_w, const float* __restrict__ S_b,
    float* __restrict__ out)
{
    const int b = blockIdx.x, tid = threadIdx.x;
    const int lane = tid & 63, wv = tid >> 6;
    __shared__ float sKh[3 * H_];
    __shared__ float sscore[N_];
    __shared__ float sred[16];
    __shared__ int sidx[4];

    const float* Ub = U + (size_t)b * 3 * H_;
    const float* Gb = G + (size_t)b * 3 * H_;

    float p0 = 0.f, p1 = 0.f, p2 = 0.f;
    for (int j = tid; j < H_; j += 256) {
        const float ww = W_w[j];
        p0 += Ub[j] * ww; p1 += Ub[H_ + j] * ww; p2 += Ub[2 * H_ + j] * ww;
    }
    p0 = wsum(p0); p1 = wsum(p1); p2 = wsum(p2);
    if (lane == 0) { sred[wv * 3 + 0] = p0; sred[wv * 3 + 1] = p1; sred[wv * 3 + 2] = p2; }
    __syncthreads();
    const float wb = W_b[0];
    const float l0 = sred[0] + sred[3] + sred[6] + sred[9]  + wb;
    const float l1 = sred[1] + sred[4] + sred[7] + sred[10] + wb;
    const float l2 = sred[2] + sred[5] + sred[8] + sred[11] + wb;
    const float mx = fmaxf(l0, fmaxf(l1, l2));
    const float e0 = expf(l0 - mx), e1 = expf(l1 - mx), e2 = expf(l2 - mx);
    const float inv = 1.f / (e0 + e1 + e2);
    const float wd0 = e0 * inv * De[b * 3 + 0];
    const float wd1 = e1 * inv * De[b * 3 + 1];
    const float wd2 = e2 * inv * De[b * 3 + 2];
    __syncthreads();

    for (int j = tid; j < H_; j += 256) {
        sKh[j]          = wd0 * Gb[j];
        sKh[H_ + j]     = wd1 * Gb[H_ + j];
        sKh[2 * H_ + j] = wd2 * Gb[2 * H_ + j];
    }
    __syncthreads();

    float q0 = 0.f, q1 = 0.f, q2 = 0.f;
    for (int j = tid; j < H_; j += 256) {
        const float sw2 = S_w[j];
        q0 += sKh[j] * sw2; q1 += sKh[H_ + j] * sw2; q2 += sKh[2 * H_ + j] * sw2;
    }
    q0 = wsum(q0); q1 = wsum(q1); q2 = wsum(q2);
    if (lane == 0) { sred[wv * 3 + 0] = q0; sred[wv * 3 + 1] = q1; sred[wv * 3 + 2] = q2; }
    __syncthreads();
    q0 = sred[0] + sred[3] + sred[6] + sred[9];
    q1 = sred[1] + sred[4] + sred[7] + sred[10];
    q2 = sred[2] + sred[5] + sred[8] + sred[11];

    const float sb0 = S_b[0];
    const float* av = aind + b * N_;
    const float* bv2 = bind + b * N_;
    const float* dv = Dv + b * N_;
    const float* sv = speak_all + (size_t)b * 3 * N_;
    for (int n = tid; n < N_; n += 256)
        sscore[n] = dv[n] * (av[n] * q0 + bv2[n] * q1 + sv[n] * q2) + sb0;
    __syncthreads();

    int r0;
    {
        float best = -INFINITY; int bi = N_;
        for (int n = tid; n < N_; n += 256) {
            const float s = sscore[n];
            if (s > best || (s == best && n < bi)) { best = s; bi = n; }
        }
#pragma unroll
        for (int off = 32; off > 0; off >>= 1) {
            const float ov = __shfl_xor(best, off); const int oi = __shfl_xor(bi, off);
            if (ov > best || (ov == best && oi < bi)) { best = ov; bi = oi; }
        }
        if (lane == 0) { sred[wv] = best; sidx[wv] = bi; }
        __syncthreads();
        float v = -INFINITY; int i = N_;
        for (int k = 0; k < 4; ++k)
            if (sred[k] > v || (sred[k] == v && sidx[k] < i)) { v = sred[k]; i = sidx[k]; }
        r0 = i;
    }
    __syncthreads();
    int r1;
    {
        float best = -INFINITY; int bi = N_;
        for (int n = tid; n < N_; n += 256) {
            if (n == r0) continue;
            const float s = sscore[n];
            if (s > best || (s == best && n < bi)) { best = s; bi = n; }
        }
#pragma unroll
        for (int off = 32; off > 0; off >>= 1) {
            const float ov = __shfl_xor(best, off); const int oi = __shfl_xor(bi, off);
            if (ov > best || (ov == best && oi < bi)) { best = ov; bi = oi; }
        }
        if (lane == 0) { sred[wv] = best; sidx[wv] = bi; }
        __syncthreads();
        float v = -INFINITY; int i = N_;
        for (int k = 0; k < 4; ++k)
            if (sred[k] > v || (sred[k] == v && sidx[k] < i)) { v = sred[k]; i = sidx[k]; }
        r1 = i;
    }

    float* ob = out + (size_t)b * 2 * H_;
    {
        const float d = dv[r0], wa = av[r0], wbn = bv2[r0], wsv = sv[r0];
        for (int j = tid; j < H_; j += 256)
            ob[j] = d * (wa * sKh[j] + wbn * sKh[H_ + j] + wsv * sKh[2 * H_ + j]);
    }
    {
        const float d = dv[r1], wa = av[r1], wbn = bv2[r1], wsv = sv[r1];
        for (int j = tid; j < H_; j += 256)
            ob[H_ + j] = d * (wa * sKh[j] + wbn * sKh[H_ + j] + wsv * sKh[2 * H_ + j]);
    }
}

extern "C" void kernel_launch(void* const* d_in, const int* in_sizes, int n_in,
                              void* d_out, int out_size, void* d_ws, size_t ws_size,
                              hipStream_t stream)
{
    const float* h         = (const float*)d_in[0];   // (B,N,H)
    const float* att       = (const float*)d_in[1];   // (B,1,N,N)
    const int*   a_idx     = (const int*)d_in[2];     // (B,8)
    const int*   b_idx     = (const int*)d_in[3];     // (B,8)
    const float* speak_all = (const float*)d_in[5];   // (B,3,N)
    const float* W_w       = (const float*)d_in[6];   // (1,H)
    const float* W_b       = (const float*)d_in[7];   // (1,)
    const float* S_w       = (const float*)d_in[8];   // (1,H)
    const float* S_b       = (const float*)d_in[9];   // (1,)
    float* out = (float*)d_out;

    float* ws      = (float*)d_ws;
    float* aind    = ws;                              // B*N
    float* bind    = aind + B_ * N_;                  // B*N
    float* Dv      = bind + B_ * N_;                  // B*N
    float* De      = Dv + B_ * N_;                    // 96, pad 128
    int*   npadArr = (int*)(De + 128);                // 32, pad 128
    float4* comp   = (float4*)(De + 256);             // B*CMAX_ float4
    float* Hyper   = De + 256 + B_ * CMAX_ * 4;       // B*3*N
    float* UGpart  = Hyper + B_ * 3 * N_;             // B*CH_*6*H
    float* U       = UGpart + (size_t)B_ * CH_ * 6 * H_; // B*3*H
    float* G       = U + B_ * 3 * H_;                 // B*3*H

    // ---- cooperative single-kernel path ----
    int dev = 0;
    hipGetDevice(&dev);
    hipDeviceProp_t prop{};
    hipGetDeviceProperties(&prop, dev);
    int maxPerCU = 0;
    hipOccupancyMaxActiveBlocksPerMultiprocessor(&maxPerCU, fused_all, 256, 0);
    bool coop = (prop.cooperativeLaunch != 0) && (maxPerCU > 0);
    int grid = 0;
    if (coop) {
        grid = maxPerCU * prop.multiProcessorCount;
        if (grid > 1024) grid = 1024;
        if (grid < 64) coop = false;
    }
    if (coop) {
        void* args[] = {
            (void*)&h, (void*)&att, (void*)&a_idx, (void*)&b_idx, (void*)&speak_all,
            (void*)&W_w, (void*)&W_b, (void*)&S_w, (void*)&S_b, (void*)&out,
            (void*)&aind, (void*)&bind, (void*)&Dv, (void*)&De,
            (void*)&npadArr, (void*)&comp, (void*)&Hyper, (void*)&UGpart,
            (void*)&U, (void*)&G };
        hipError_t e = hipLaunchCooperativeKernel(fused_all, dim3(grid), dim3(256),
                                                  args, 0, stream);
        if (e == hipSuccess) return;
    }

    // ---- fallback: round-6 five-kernel chain ----
    k1_ind<<<B_, 1024, 0, stream>>>(att, a_idx, b_idx, speak_all, aind, bind, Dv, De, comp, npadArr);
    k2_hyper<<<dim3(32, B_), 256, 0, stream>>>(att, comp, npadArr, Hyper);
    k4_ug<<<dim3(CH_, B_), 192, 0, stream>>>(h, Hyper, Dv, UGpart);
    k4b_red<<<144, 256, 0, stream>>>(UGpart, U, G);
    k5_fin<<<B_, 256, 0, stream>>>(U, G, De, Dv, aind, bind, speak_all, W_w, W_b, S_w, S_b, out);
}

// Round 8
// 258.202 us; speedup vs baseline: 1.9048x; 1.9048x over previous
//
#include <hip/hip_runtime.h>
#include <math.h>

#define B_ 32
#define N_ 1024
#define H_ 768
#define A_ 8
#define TOPK_ 20
#define CH_ 32
#define CMAX_ 1280

__device__ __forceinline__ float wsum(float x) {
#pragma unroll
    for (int off = 32; off > 0; off >>= 1) x += __shfl_xor(x, off);
    return x;
}

// ---------------------------------------------------------------------------
// K1: top-20 indicators, Dv, De, compacted+padded active-row list; zeroes the
// per-batch completion counters.  grid=B, block=1024.
// ---------------------------------------------------------------------------
__global__ __launch_bounds__(1024) void k1_ind(
    const float* __restrict__ att, const int* __restrict__ a_idx,
    const int* __restrict__ b_idx, const float* __restrict__ speak_all,
    float* __restrict__ aind, float* __restrict__ bind,
    float* __restrict__ Dv, float* __restrict__ De,
    float4* __restrict__ comp, int* __restrict__ npadArr, int* __restrict__ cnt)
{
    const int b = blockIdx.x;
    const int tid = threadIdx.x;
    const int w = tid >> 6, lane = tid & 63;
    __shared__ float s_ind[2][N_];
    __shared__ float s_red[3][16];
    __shared__ int wcnt[16];
    __shared__ int woff[17];

    if (b == 0 && tid < 64) cnt[tid] = 0;   // reset flags every call

    s_ind[0][tid] = 0.f;
    s_ind[1][tid] = 0.f;
    __syncthreads();

    const int which = w >> 3;
    const int r = w & 7;
    const int idx = which ? b_idx[b * A_ + r] : a_idx[b * A_ + r];
    if (idx != 0) {   // mask = (idx != 0)
        const float* row = att + ((size_t)b * N_ + idx) * N_;
        float v[16];
#pragma unroll
        for (int k = 0; k < 16; ++k) v[k] = row[(k << 6) + lane];
        float* dst = s_ind[which];
        for (int t2 = 0; t2 < TOPK_; ++t2) {
            float bv = v[0]; int bk = 0;
#pragma unroll
            for (int k = 1; k < 16; ++k)
                if (v[k] > bv) { bv = v[k]; bk = k; }   // lower col wins ties
            int bc = (bk << 6) + lane;
#pragma unroll
            for (int off = 32; off > 0; off >>= 1) {
                float ov = __shfl_xor(bv, off);
                int oc = __shfl_xor(bc, off);
                if (ov > bv || (ov == bv && oc < bc)) { bv = ov; bc = oc; }
            }
            if (lane == 0) dst[bc] = 1.f;   // benign same-value races
            if (lane == (bc & 63)) v[bc >> 6] = -INFINITY;
        }
    }
    __syncthreads();

    const float sa = s_ind[0][tid], sb = s_ind[1][tid];
    const float ss = speak_all[(size_t)b * 3 * N_ + tid];
    aind[b * N_ + tid] = sa;
    bind[b * N_ + tid] = sb;
    Dv[b * N_ + tid] = 1.f / sqrtf(sa + sb + ss + 1.f);

    float p[3] = {sa, sb, ss};
#pragma unroll
    for (int e = 0; e < 3; ++e) {
        float x = wsum(p[e]);
        if (lane == 0) s_red[e][w] = x;
    }

    const bool act = (sa + sb + ss) > 0.f;
    const unsigned long long m = __ballot(act);
    const int wrank = (int)__popcll(m & ((1ull << lane) - 1ull));
    if (lane == 0) wcnt[w] = (int)__popcll(m);
    __syncthreads();
    if (tid == 0) {
        int s = 0;
        for (int i = 0; i < 16; ++i) { woff[i] = s; s += wcnt[i]; }
        woff[16] = s;
        npadArr[b] = (s + 255) & ~255;
    }
    if (tid < 3) {
        float s = 0.f;
        for (int i = 0; i < 16; ++i) s += s_red[tid][i];
        De[b * 3 + tid] = 1.f / sqrtf(s);
    }
    __syncthreads();
    const int nact = woff[16];
    const int npad = (nact + 255) & ~255;
    if (act)
        comp[(size_t)b * CMAX_ + woff[w] + wrank] = make_float4(__int_as_float(tid), sa, sb, ss);
    for (int i = nact + tid; i < npad; i += 1024)
        comp[(size_t)b * CMAX_ + i] = make_float4(__int_as_float(0), 0.f, 0.f, 0.f);
}

// ---------------------------------------------------------------------------
// kBC: fused Hyper (phase B) + U/G partials (phase C) with per-batch
// release/acquire flags.  grid=1024 (all co-resident: LDS 29.7KB -> 5/CU,
// launch_bounds(256,4) -> >=4/CU), block=256.
// Block w: B-item (b=w>>5, chunk=w&31) -> fence+atomicAdd(cnt[b]) ->
// spin until cnt[b]==32 -> C-item (same b, chunk).  Produce-before-consume:
// every block finishes its B before waiting, so no deadlock.
// ---------------------------------------------------------------------------
__global__ __launch_bounds__(256, 4) void kBC(
    const float* __restrict__ att, const float4* __restrict__ comp,
    const int* __restrict__ npadArr, const float* __restrict__ h,
    const float* __restrict__ Dv, float* __restrict__ Hyper,
    float* __restrict__ UGpart, int* __restrict__ cnt)
{
    const int w = blockIdx.x;
    const int b = w >> 5, chunk = w & 31;
    const int t = threadIdx.x;
    __shared__ float4 scomp[1024];   // 16 KB (phase C aliases as sH)
    __shared__ float scr[3328];      // 13 KB (phase C aliases as sw6)
    __shared__ float smz[8];

    // ================= phase B: Hyper slice =================
    const int npad = npadArr[b];
    for (int i = t; i < npad; i += 256) scomp[i] = comp[(size_t)b * CMAX_ + i];
    __syncthreads();
    const int cx = t & 7, ig = t >> 3;
    {
        float a0x=0,a0y=0,a0z=0,a0w=0, a1x=0,a1y=0,a1z=0,a1w=0, a2x=0,a2y=0,a2z=0,a2w=0;
        const float* bb = att + (size_t)b * N_ * N_ + chunk * 32 + cx * 4;
#pragma unroll 4
        for (int i = ig; i < npad; i += 32) {
            const float4 c = scomp[i];
            const float4 v = *(const float4*)(bb + (size_t)__float_as_int(c.x) * N_);
            a0x += c.y*v.x; a0y += c.y*v.y; a0z += c.y*v.z; a0w += c.y*v.w;
            a1x += c.z*v.x; a1y += c.z*v.y; a1z += c.z*v.z; a1w += c.z*v.w;
            a2x += c.w*v.x; a2y += c.w*v.y; a2z += c.w*v.z; a2w += c.w*v.w;
        }
        __syncthreads();
        float vals[12] = {a0x,a0y,a0z,a0w, a1x,a1y,a1z,a1w, a2x,a2y,a2z,a2w};
#pragma unroll
        for (int k = 0; k < 12; ++k) scr[t * 13 + k] = vals[k];
        __syncthreads();
        for (int s2 = 16; s2 > 0; s2 >>= 1) {
            if (ig < s2) {
#pragma unroll
                for (int k = 0; k < 12; ++k)
                    scr[t * 13 + k] += scr[(t + s2 * 8) * 13 + k];
            }
            __syncthreads();
        }
        if (ig == 0) {
#pragma unroll
            for (int e = 0; e < 3; ++e)
#pragma unroll
                for (int j = 0; j < 4; ++j)
                    Hyper[(size_t)(b * 3 + e) * N_ + chunk * 32 + cx * 4 + j] =
                        scr[t * 13 + e * 4 + j];
        }
    }
    __threadfence();          // release: Hyper stores device-visible
    __syncthreads();
    if (t == 0) atomicAdd(&cnt[b], 1);

    // ================= wait for batch b's 32 B-items =================
    if (t == 0) {
        while (atomicAdd(&cnt[b], 0) < 32) __builtin_amdgcn_s_sleep(2);
    }
    __syncthreads();
    __threadfence();          // acquire: invalidate stale Hyper lines

    // ================= phase C: softmax stats + U/G partials =================
    float* sH = (float*)scomp;       // 3072 floats
    float* sw6 = scr;                // [6][32] flattened
    for (int i = t; i < 768; i += 256)
        ((float4*)sH)[i] = ((const float4*)(Hyper + (size_t)b * 3 * N_))[i];
    __syncthreads();
    const int wv = t >> 6, lane = t & 63;
    if (wv < 3) {
        const float* He = sH + wv * N_;
        float m = -INFINITY;
        for (int n = lane; n < N_; n += 64) m = fmaxf(m, He[n]);
#pragma unroll
        for (int off = 32; off > 0; off >>= 1) m = fmaxf(m, __shfl_xor(m, off));
        float z = 0.f;
        for (int n = lane; n < N_; n += 64) z += expf(He[n] - m);
        z = wsum(z);
        if (lane == 0) { smz[wv] = m; smz[4 + wv] = 1.f / z; }
    }
    __syncthreads();
    const int n0 = chunk * 32;
    if (t < 96) {
        const int e = t >> 5, r = t & 31;
        const float Hv = sH[e * N_ + n0 + r];
        sw6[e * 32 + r] = expf(Hv - smz[e]) * smz[4 + e];
        sw6[96 + e * 32 + r] = Hv * Dv[b * N_ + n0 + r];
    }
    __syncthreads();

    // 256 threads x float3 = 768 cols, all lanes active
    float u00=0,u01=0,u02=0, u10=0,u11=0,u12=0, u20=0,u21=0,u22=0;
    float g00=0,g01=0,g02=0, g10=0,g11=0,g12=0, g20=0,g21=0,g22=0;
    const float* base = h + (size_t)b * N_ * H_ + (size_t)n0 * H_ + t * 3;
#pragma unroll 8
    for (int r = 0; r < 32; ++r) {
        const float3 v = *(const float3*)(base + (size_t)r * H_);
        const float w0 = sw6[r], w1 = sw6[32 + r], w2 = sw6[64 + r];
        const float g0 = sw6[96 + r], g1 = sw6[128 + r], g2 = sw6[160 + r];
        u00 += w0*v.x; u01 += w0*v.y; u02 += w0*v.z;
        u10 += w1*v.x; u11 += w1*v.y; u12 += w1*v.z;
        u20 += w2*v.x; u21 += w2*v.y; u22 += w2*v.z;
        g00 += g0*v.x; g01 += g0*v.y; g02 += g0*v.z;
        g10 += g1*v.x; g11 += g1*v.y; g12 += g1*v.z;
        g20 += g2*v.x; g21 += g2*v.y; g22 += g2*v.z;
    }
    float* up = UGpart + (size_t)(b * CH_ + chunk) * 6 * H_ + t * 3;
    up[0] = u00; up[1] = u01; up[2] = u02;
    up[H_ + 0] = u10; up[H_ + 1] = u11; up[H_ + 2] = u12;
    up[2*H_ + 0] = u20; up[2*H_ + 1] = u21; up[2*H_ + 2] = u22;
    up[3*H_ + 0] = g00; up[3*H_ + 1] = g01; up[3*H_ + 2] = g02;
    up[4*H_ + 0] = g10; up[4*H_ + 1] = g11; up[4*H_ + 2] = g12;
    up[5*H_ + 0] = g20; up[5*H_ + 1] = g21; up[5*H_ + 2] = g22;
}

// ---------------------------------------------------------------------------
// K45: reduce UGpart into LDS U/G, then finalize.  grid=B, block=256.
// ---------------------------------------------------------------------------
__global__ __launch_bounds__(256) void k45_fin(
    const float* __restrict__ UGpart,
    const float* __restrict__ De, const float* __restrict__ Dv,
    const float* __restrict__ aind, const float* __restrict__ bind,
    const float* __restrict__ speak_all,
    const float* __restrict__ W_w, const float* __restrict__ W_b,
    const float* __restrict__ S_w, const float* __restrict__ S_b,
    float* __restrict__ out)
{
    const int b = blockIdx.x, tid = threadIdx.x;
    const int lane = tid & 63, wv = tid >> 6;
    __shared__ float sUG[6 * H_];
    __shared__ float sKh[3 * H_];
    __shared__ float sscore[N_];
    __shared__ float sred[16];
    __shared__ int sidx[4];

    {
        const float* p = UGpart + (size_t)b * CH_ * 6 * H_;
        for (int slot = tid; slot < 1152; slot += 256) {
            const int off = slot * 4;
            float4 a0 = make_float4(0,0,0,0), a1 = make_float4(0,0,0,0);
            float4 a2 = make_float4(0,0,0,0), a3 = make_float4(0,0,0,0);
#pragma unroll
            for (int c = 0; c < CH_; c += 4) {
                const float4 v0 = *(const float4*)(p + (size_t)(c + 0) * 6 * H_ + off);
                const float4 v1 = *(const float4*)(p + (size_t)(c + 1) * 6 * H_ + off);
                const float4 v2 = *(const float4*)(p + (size_t)(c + 2) * 6 * H_ + off);
                const float4 v3 = *(const float4*)(p + (size_t)(c + 3) * 6 * H_ + off);
                a0.x += v0.x; a0.y += v0.y; a0.z += v0.z; a0.w += v0.w;
                a1.x += v1.x; a1.y += v1.y; a1.z += v1.z; a1.w += v1.w;
                a2.x += v2.x; a2.y += v2.y; a2.z += v2.z; a2.w += v2.w;
                a3.x += v3.x; a3.y += v3.y; a3.z += v3.z; a3.w += v3.w;
            }
            sUG[off + 0] = a0.x + a1.x + a2.x + a3.x;
            sUG[off + 1] = a0.y + a1.y + a2.y + a3.y;
            sUG[off + 2] = a0.z + a1.z + a2.z + a3.z;
            sUG[off + 3] = a0.w + a1.w + a2.w + a3.w;
        }
    }
    __syncthreads();

    const float* Ub = sUG;
    const float* Gb = sUG + 3 * H_;

    float p0 = 0.f, p1 = 0.f, p2 = 0.f;
    for (int j = tid; j < H_; j += 256) {
        const float ww = W_w[j];
        p0 += Ub[j] * ww; p1 += Ub[H_ + j] * ww; p2 += Ub[2 * H_ + j] * ww;
    }
    p0 = wsum(p0); p1 = wsum(p1); p2 = wsum(p2);
    if (lane == 0) { sred[wv * 3 + 0] = p0; sred[wv * 3 + 1] = p1; sred[wv * 3 + 2] = p2; }
    __syncthreads();
    const float wb = W_b[0];
    const float l0 = sred[0] + sred[3] + sred[6] + sred[9]  + wb;
    const float l1 = sred[1] + sred[4] + sred[7] + sred[10] + wb;
    const float l2 = sred[2] + sred[5] + sred[8] + sred[11] + wb;
    const float mx = fmaxf(l0, fmaxf(l1, l2));
    const float e0 = expf(l0 - mx), e1 = expf(l1 - mx), e2 = expf(l2 - mx);
    const float inv = 1.f / (e0 + e1 + e2);
    const float wd0 = e0 * inv * De[b * 3 + 0];
    const float wd1 = e1 * inv * De[b * 3 + 1];
    const float wd2 = e2 * inv * De[b * 3 + 2];
    __syncthreads();

    for (int j = tid; j < H_; j += 256) {
        sKh[j]          = wd0 * Gb[j];
        sKh[H_ + j]     = wd1 * Gb[H_ + j];
        sKh[2 * H_ + j] = wd2 * Gb[2 * H_ + j];
    }
    __syncthreads();

    float q0 = 0.f, q1 = 0.f, q2 = 0.f;
    for (int j = tid; j < H_; j += 256) {
        const float sw2 = S_w[j];
        q0 += sKh[j] * sw2; q1 += sKh[H_ + j] * sw2; q2 += sKh[2 * H_ + j] * sw2;
    }
    q0 = wsum(q0); q1 = wsum(q1); q2 = wsum(q2);
    if (lane == 0) { sred[wv * 3 + 0] = q0; sred[wv * 3 + 1] = q1; sred[wv * 3 + 2] = q2; }
    __syncthreads();
    q0 = sred[0] + sred[3] + sred[6] + sred[9];
    q1 = sred[1] + sred[4] + sred[7] + sred[10];
    q2 = sred[2] + sred[5] + sred[8] + sred[11];

    const float sb0 = S_b[0];
    const float* av = aind + b * N_;
    const float* bv2 = bind + b * N_;
    const float* dv = Dv + b * N_;
    const float* sv = speak_all + (size_t)b * 3 * N_;
    for (int n = tid; n < N_; n += 256)
        sscore[n] = dv[n] * (av[n] * q0 + bv2[n] * q1 + sv[n] * q2) + sb0;
    __syncthreads();

    int r0;
    {
        float best = -INFINITY; int bi = N_;
        for (int n = tid; n < N_; n += 256) {
            const float s = sscore[n];
            if (s > best || (s == best && n < bi)) { best = s; bi = n; }
        }
#pragma unroll
        for (int off = 32; off > 0; off >>= 1) {
            const float ov = __shfl_xor(best, off); const int oi = __shfl_xor(bi, off);
            if (ov > best || (ov == best && oi < bi)) { best = ov; bi = oi; }
        }
        if (lane == 0) { sred[wv] = best; sidx[wv] = bi; }
        __syncthreads();
        float v = -INFINITY; int i = N_;
        for (int k = 0; k < 4; ++k)
            if (sred[k] > v || (sred[k] == v && sidx[k] < i)) { v = sred[k]; i = sidx[k]; }
        r0 = i;
    }
    __syncthreads();
    int r1;
    {
        float best = -INFINITY; int bi = N_;
        for (int n = tid; n < N_; n += 256) {
            if (n == r0) continue;
            const float s = sscore[n];
            if (s > best || (s == best && n < bi)) { best = s; bi = n; }
        }
#pragma unroll
        for (int off = 32; off > 0; off >>= 1) {
            const float ov = __shfl_xor(best, off); const int oi = __shfl_xor(bi, off);
            if (ov > best || (ov == best && oi < bi)) { best = ov; bi = oi; }
        }
        if (lane == 0) { sred[wv] = best; sidx[wv] = bi; }
        __syncthreads();
        float v = -INFINITY; int i = N_;
        for (int k = 0; k < 4; ++k)
            if (sred[k] > v || (sred[k] == v && sidx[k] < i)) { v = sred[k]; i = sidx[k]; }
        r1 = i;
    }

    float* ob = out + (size_t)b * 2 * H_;
    {
        const float d = dv[r0], wa = av[r0], wbn = bv2[r0], wsv = sv[r0];
        for (int j = tid; j < H_; j += 256)
            ob[j] = d * (wa * sKh[j] + wbn * sKh[H_ + j] + wsv * sKh[2 * H_ + j]);
    }
    {
        const float d = dv[r1], wa = av[r1], wbn = bv2[r1], wsv = sv[r1];
        for (int j = tid; j < H_; j += 256)
            ob[H_ + j] = d * (wa * sKh[j] + wbn * sKh[H_ + j] + wsv * sKh[2 * H_ + j]);
    }
}

extern "C" void kernel_launch(void* const* d_in, const int* in_sizes, int n_in,
                              void* d_out, int out_size, void* d_ws, size_t ws_size,
                              hipStream_t stream)
{
    const float* h         = (const float*)d_in[0];   // (B,N,H)
    const float* att       = (const float*)d_in[1];   // (B,1,N,N)
    const int*   a_idx     = (const int*)d_in[2];     // (B,8)
    const int*   b_idx     = (const int*)d_in[3];     // (B,8)
    const float* speak_all = (const float*)d_in[5];   // (B,3,N)
    const float* W_w       = (const float*)d_in[6];   // (1,H)
    const float* W_b       = (const float*)d_in[7];   // (1,)
    const float* S_w       = (const float*)d_in[8];   // (1,H)
    const float* S_b       = (const float*)d_in[9];   // (1,)
    float* out = (float*)d_out;

    float* ws      = (float*)d_ws;
    float* aind    = ws;                              // B*N
    float* bind    = aind + B_ * N_;                  // B*N
    float* Dv      = bind + B_ * N_;                  // B*N
    float* De      = Dv + B_ * N_;                    // 96, pad 128
    int*   npadArr = (int*)(De + 128);                // 32, pad 64
    int*   cnt     = npadArr + 64;                    // 32, pad 64
    float4* comp   = (float4*)(npadArr + 128);        // B*CMAX_ float4
    float* Hyper   = (float*)(comp + (size_t)B_ * CMAX_);   // B*3*N
    float* UGpart  = Hyper + B_ * 3 * N_;             // B*CH_*6*H

    k1_ind<<<B_, 1024, 0, stream>>>(att, a_idx, b_idx, speak_all, aind, bind,
                                    Dv, De, comp, npadArr, cnt);
    kBC<<<B_ * CH_, 256, 0, stream>>>(att, comp, npadArr, h, Dv, Hyper, UGpart, cnt);
    k45_fin<<<B_, 256, 0, stream>>>(UGpart, De, Dv, aind, bind, speak_all,
                                    W_w, W_b, S_w, S_b, out);
}

// Round 9
// 80.084 us; speedup vs baseline: 6.1413x; 3.2241x over previous
//
#include <hip/hip_runtime.h>
#include <math.h>

#define B_ 32
#define N_ 1024
#define H_ 768
#define A_ 8
#define TOPK_ 20
#define CH_ 32
#define CMAX_ 1280

__device__ __forceinline__ float wsum(float x) {
#pragma unroll
    for (int off = 32; off > 0; off >>= 1) x += __shfl_xor(x, off);
    return x;
}

// ---------------------------------------------------------------------------
// K1: top-20 indicators, Dv, De, compacted active-row list (padded to x128).
// grid=B, block=1024.
// ---------------------------------------------------------------------------
__global__ __launch_bounds__(1024) void k1_ind(
    const float* __restrict__ att, const int* __restrict__ a_idx,
    const int* __restrict__ b_idx, const float* __restrict__ speak_all,
    float* __restrict__ aind, float* __restrict__ bind,
    float* __restrict__ Dv, float* __restrict__ De,
    float4* __restrict__ comp, int* __restrict__ npadArr)
{
    const int b = blockIdx.x;
    const int tid = threadIdx.x;
    const int w = tid >> 6, lane = tid & 63;
    __shared__ float s_ind[2][N_];
    __shared__ float s_red[3][16];
    __shared__ int wcnt[16];
    __shared__ int woff[17];

    s_ind[0][tid] = 0.f;
    s_ind[1][tid] = 0.f;
    __syncthreads();

    const int which = w >> 3;
    const int r = w & 7;
    const int idx = which ? b_idx[b * A_ + r] : a_idx[b * A_ + r];
    if (idx != 0) {   // mask = (idx != 0)
        const float* row = att + ((size_t)b * N_ + idx) * N_;
        float v[16];
#pragma unroll
        for (int k = 0; k < 16; ++k) v[k] = row[(k << 6) + lane];
        float* dst = s_ind[which];
        for (int t2 = 0; t2 < TOPK_; ++t2) {
            float bv = v[0]; int bk = 0;
#pragma unroll
            for (int k = 1; k < 16; ++k)
                if (v[k] > bv) { bv = v[k]; bk = k; }   // lower col wins ties
            int bc = (bk << 6) + lane;
#pragma unroll
            for (int off = 32; off > 0; off >>= 1) {
                float ov = __shfl_xor(bv, off);
                int oc = __shfl_xor(bc, off);
                if (ov > bv || (ov == bv && oc < bc)) { bv = ov; bc = oc; }
            }
            if (lane == 0) dst[bc] = 1.f;   // benign same-value races
            if (lane == (bc & 63)) v[bc >> 6] = -INFINITY;
        }
    }
    __syncthreads();

    const float sa = s_ind[0][tid], sb = s_ind[1][tid];
    const float ss = speak_all[(size_t)b * 3 * N_ + tid];
    aind[b * N_ + tid] = sa;
    bind[b * N_ + tid] = sb;
    Dv[b * N_ + tid] = 1.f / sqrtf(sa + sb + ss + 1.f);

    float p[3] = {sa, sb, ss};
#pragma unroll
    for (int e = 0; e < 3; ++e) {
        float x = wsum(p[e]);
        if (lane == 0) s_red[e][w] = x;
    }

    const bool act = (sa + sb + ss) > 0.f;
    const unsigned long long m = __ballot(act);
    const int wrank = (int)__popcll(m & ((1ull << lane) - 1ull));
    if (lane == 0) wcnt[w] = (int)__popcll(m);
    __syncthreads();
    if (tid == 0) {
        int s = 0;
        for (int i = 0; i < 16; ++i) { woff[i] = s; s += wcnt[i]; }
        woff[16] = s;
        npadArr[b] = (s + 127) & ~127;
    }
    if (tid < 3) {
        float s = 0.f;
        for (int i = 0; i < 16; ++i) s += s_red[tid][i];
        De[b * 3 + tid] = 1.f / sqrtf(s);
    }
    __syncthreads();
    const int nact = woff[16];
    const int npad = (nact + 127) & ~127;
    if (act)
        comp[(size_t)b * CMAX_ + woff[w] + wrank] = make_float4(__int_as_float(tid), sa, sb, ss);
    for (int i = nact + tid; i < npad; i += 1024)
        comp[(size_t)b * CMAX_ + i] = make_float4(__int_as_float(0), 0.f, 0.f, 0.f);
}

// ---------------------------------------------------------------------------
// kBC2: fused Hyper-slice + ONLINE-SOFTMAX U/G partials.  grid=(32,B), 256.
// Block (chunk,b): (1) col-slab Hyper for its 32 columns via compacted rows;
// (2) local m_c, Z_c over those 32 values; (3) stream h rows n0..n0+31 with
// weights exp(H-m_c) (U) and H*Dv (G).  NO inter-block sync anywhere.
// Writes UGpart[b][c][6][H] and MZ[b][c][8] = {m0,m1,m2,_,Z0,Z1,Z2,_}.
// ---------------------------------------------------------------------------
__global__ __launch_bounds__(256, 4) void kBC2(
    const float* __restrict__ att, const float4* __restrict__ comp,
    const int* __restrict__ npadArr, const float* __restrict__ h,
    const float* __restrict__ Dv,
    float* __restrict__ UGpart, float* __restrict__ MZ)
{
    const int b = blockIdx.y, chunk = blockIdx.x;
    const int n0 = chunk * 32;
    const int t = threadIdx.x;
    __shared__ float4 scomp[1024];   // 16 KB
    __shared__ float scr[3328];      // 13 KB reduce scratch (stride 13)
    __shared__ float sHy[96];        // Hyper values of this chunk
    __shared__ float sw6[192];       // exp-weights (0..95) and gg (96..191)
    __shared__ float smz[8];         // m[3] @0..2, Z[3] @4..6

    // ---- phase B: Hyper slice for cols n0..n0+31 ----
    const int npad = npadArr[b];
    for (int i = t; i < npad; i += 256) scomp[i] = comp[(size_t)b * CMAX_ + i];
    __syncthreads();
    const int cx = t & 7, ig = t >> 3;
    {
        float a0x=0,a0y=0,a0z=0,a0w=0, a1x=0,a1y=0,a1z=0,a1w=0, a2x=0,a2y=0,a2z=0,a2w=0;
        const float* bb = att + (size_t)b * N_ * N_ + n0 + cx * 4;
#pragma unroll 4
        for (int i = ig; i < npad; i += 32) {
            const float4 c = scomp[i];
            const float4 v = *(const float4*)(bb + (size_t)__float_as_int(c.x) * N_);
            a0x += c.y*v.x; a0y += c.y*v.y; a0z += c.y*v.z; a0w += c.y*v.w;
            a1x += c.z*v.x; a1y += c.z*v.y; a1z += c.z*v.z; a1w += c.z*v.w;
            a2x += c.w*v.x; a2y += c.w*v.y; a2z += c.w*v.z; a2w += c.w*v.w;
        }
        __syncthreads();
        float vals[12] = {a0x,a0y,a0z,a0w, a1x,a1y,a1z,a1w, a2x,a2y,a2z,a2w};
#pragma unroll
        for (int k = 0; k < 12; ++k) scr[t * 13 + k] = vals[k];
        __syncthreads();
        for (int s2 = 16; s2 > 0; s2 >>= 1) {
            if (ig < s2) {
#pragma unroll
                for (int k = 0; k < 12; ++k)
                    scr[t * 13 + k] += scr[(t + s2 * 8) * 13 + k];
            }
            __syncthreads();
        }
        if (ig == 0) {   // t == cx here
#pragma unroll
            for (int e = 0; e < 3; ++e)
#pragma unroll
                for (int j = 0; j < 4; ++j)
                    sHy[e * 32 + cx * 4 + j] = scr[t * 13 + e * 4 + j];
        }
    }
    __syncthreads();

    // ---- local softmax stats over this chunk's 32 values (3 waves) ----
    const int wv = t >> 6, lane = t & 63;
    if (wv < 3) {
        const float val = (lane < 32) ? sHy[wv * 32 + lane] : -INFINITY;
        float m = val;
#pragma unroll
        for (int off = 32; off > 0; off >>= 1) m = fmaxf(m, __shfl_xor(m, off));
        float z = (lane < 32) ? __expf(val - m) : 0.f;
        z = wsum(z);
        if (lane == 0) { smz[wv] = m; smz[4 + wv] = z; }
    }
    __syncthreads();
    if (t < 96) {
        const int e = t >> 5, r = t & 31;
        const float Hv = sHy[e * 32 + r];
        sw6[e * 32 + r] = __expf(Hv - smz[e]);          // unnormalized weight
        sw6[96 + e * 32 + r] = Hv * Dv[b * N_ + n0 + r];
    }
    if (t < 8) MZ[(size_t)(b * CH_ + chunk) * 8 + t] = (t < 4) ? smz[t] : smz[t];
    __syncthreads();

    // ---- phase C: stream h rows n0..n0+31 (192 threads x float4) ----
    if (t < 192) {
        float u00=0,u01=0,u02=0,u03=0, u10=0,u11=0,u12=0,u13=0, u20=0,u21=0,u22=0,u23=0;
        float g00=0,g01=0,g02=0,g03=0, g10=0,g11=0,g12=0,g13=0, g20=0,g21=0,g22=0,g23=0;
        const float* base = h + (size_t)b * N_ * H_ + (size_t)n0 * H_ + t * 4;
#pragma unroll 8
        for (int r = 0; r < 32; ++r) {
            const float4 v = *(const float4*)(base + (size_t)r * H_);
            const float w0 = sw6[r], w1 = sw6[32 + r], w2 = sw6[64 + r];
            const float g0 = sw6[96 + r], g1 = sw6[128 + r], g2 = sw6[160 + r];
            u00 += w0*v.x; u01 += w0*v.y; u02 += w0*v.z; u03 += w0*v.w;
            u10 += w1*v.x; u11 += w1*v.y; u12 += w1*v.z; u13 += w1*v.w;
            u20 += w2*v.x; u21 += w2*v.y; u22 += w2*v.z; u23 += w2*v.w;
            g00 += g0*v.x; g01 += g0*v.y; g02 += g0*v.z; g03 += g0*v.w;
            g10 += g1*v.x; g11 += g1*v.y; g12 += g1*v.z; g13 += g1*v.w;
            g20 += g2*v.x; g21 += g2*v.y; g22 += g2*v.z; g23 += g2*v.w;
        }
        float* up = UGpart + (size_t)(b * CH_ + chunk) * 6 * H_ + t * 4;
        *(float4*)(up)        = make_float4(u00,u01,u02,u03);
        *(float4*)(up + H_)   = make_float4(u10,u11,u12,u13);
        *(float4*)(up + 2*H_) = make_float4(u20,u21,u22,u23);
        *(float4*)(up + 3*H_) = make_float4(g00,g01,g02,g03);
        *(float4*)(up + 4*H_) = make_float4(g10,g11,g12,g13);
        *(float4*)(up + 5*H_) = make_float4(g20,g21,g22,g23);
    }
}

// ---------------------------------------------------------------------------
// K45: combine online-softmax partials, then finalize.  grid=B, block=256.
// ---------------------------------------------------------------------------
__global__ __launch_bounds__(256) void k45_fin(
    const float* __restrict__ UGpart, const float* __restrict__ MZ,
    const float* __restrict__ De, const float* __restrict__ Dv,
    const float* __restrict__ aind, const float* __restrict__ bind,
    const float* __restrict__ speak_all,
    const float* __restrict__ W_w, const float* __restrict__ W_b,
    const float* __restrict__ S_w, const float* __restrict__ S_b,
    float* __restrict__ out)
{
    const int b = blockIdx.x, tid = threadIdx.x;
    const int lane = tid & 63, wv = tid >> 6;
    __shared__ float sUG[6 * H_];
    __shared__ float sKh[3 * H_];
    __shared__ float sscore[N_];
    __shared__ float sMZ[256];       // raw MZ
    __shared__ float sscale[CH_ * 4];
    __shared__ float siZ[4];
    __shared__ float sred[16];
    __shared__ int sidx[4];

    // load MZ, compute global m, per-chunk scales, Z
    if (tid < CH_ * 8) sMZ[tid] = MZ[(size_t)b * CH_ * 8 + tid];
    __syncthreads();
    if (tid < 3) {
        float m = -INFINITY;
        for (int c = 0; c < CH_; ++c) m = fmaxf(m, sMZ[c * 8 + tid]);
        float Z = 0.f;
        for (int c = 0; c < CH_; ++c) {
            const float sc = __expf(sMZ[c * 8 + tid] - m);
            sscale[c * 4 + tid] = sc;
            Z += sc * sMZ[c * 8 + 4 + tid];
        }
        siZ[tid] = 1.f / Z;
    }
    __syncthreads();

    // reduce 32 chunks: U scaled, G plain
    {
        const float* p = UGpart + (size_t)b * CH_ * 6 * H_;
        for (int slot = tid; slot < 1152; slot += 256) {
            const int s = slot / 192;          // 0..5
            const int off = slot * 4;
            float4 a0 = make_float4(0,0,0,0), a1 = make_float4(0,0,0,0);
            if (s < 3) {
#pragma unroll
                for (int c = 0; c < CH_; c += 2) {
                    const float w0 = sscale[(c+0) * 4 + s];
                    const float w1 = sscale[(c+1) * 4 + s];
                    const float4 v0 = *(const float4*)(p + (size_t)(c+0) * 6 * H_ + off);
                    const float4 v1 = *(const float4*)(p + (size_t)(c+1) * 6 * H_ + off);
                    a0.x += w0*v0.x; a0.y += w0*v0.y; a0.z += w0*v0.z; a0.w += w0*v0.w;
                    a1.x += w1*v1.x; a1.y += w1*v1.y; a1.z += w1*v1.z; a1.w += w1*v1.w;
                }
            } else {
#pragma unroll
                for (int c = 0; c < CH_; c += 2) {
                    const float4 v0 = *(const float4*)(p + (size_t)(c+0) * 6 * H_ + off);
                    const float4 v1 = *(const float4*)(p + (size_t)(c+1) * 6 * H_ + off);
                    a0.x += v0.x; a0.y += v0.y; a0.z += v0.z; a0.w += v0.w;
                    a1.x += v1.x; a1.y += v1.y; a1.z += v1.z; a1.w += v1.w;
                }
            }
            sUG[off + 0] = a0.x + a1.x;
            sUG[off + 1] = a0.y + a1.y;
            sUG[off + 2] = a0.z + a1.z;
            sUG[off + 3] = a0.w + a1.w;
        }
    }
    __syncthreads();

    const float* Ub = sUG;            // unnormalized exp-weighted sums
    const float* Gb = sUG + 3 * H_;   // exact

    float p0 = 0.f, p1 = 0.f, p2 = 0.f;
    for (int j = tid; j < H_; j += 256) {
        const float ww = W_w[j];
        p0 += Ub[j] * ww; p1 += Ub[H_ + j] * ww; p2 += Ub[2 * H_ + j] * ww;
    }
    p0 = wsum(p0); p1 = wsum(p1); p2 = wsum(p2);
    if (lane == 0) { sred[wv * 3 + 0] = p0; sred[wv * 3 + 1] = p1; sred[wv * 3 + 2] = p2; }
    __syncthreads();
    const float wb = W_b[0];
    const float l0 = (sred[0] + sred[3] + sred[6] + sred[9])  * siZ[0] + wb;
    const float l1 = (sred[1] + sred[4] + sred[7] + sred[10]) * siZ[1] + wb;
    const float l2 = (sred[2] + sred[5] + sred[8] + sred[11]) * siZ[2] + wb;
    const float mx = fmaxf(l0, fmaxf(l1, l2));
    const float e0 = expf(l0 - mx), e1 = expf(l1 - mx), e2 = expf(l2 - mx);
    const float inv = 1.f / (e0 + e1 + e2);
    const float wd0 = e0 * inv * De[b * 3 + 0];
    const float wd1 = e1 * inv * De[b * 3 + 1];
    const float wd2 = e2 * inv * De[b * 3 + 2];
    __syncthreads();

    for (int j = tid; j < H_; j += 256) {
        sKh[j]          = wd0 * Gb[j];
        sKh[H_ + j]     = wd1 * Gb[H_ + j];
        sKh[2 * H_ + j] = wd2 * Gb[2 * H_ + j];
    }
    __syncthreads();

    float q0 = 0.f, q1 = 0.f, q2 = 0.f;
    for (int j = tid; j < H_; j += 256) {
        const float sw2 = S_w[j];
        q0 += sKh[j] * sw2; q1 += sKh[H_ + j] * sw2; q2 += sKh[2 * H_ + j] * sw2;
    }
    q0 = wsum(q0); q1 = wsum(q1); q2 = wsum(q2);
    if (lane == 0) { sred[wv * 3 + 0] = q0; sred[wv * 3 + 1] = q1; sred[wv * 3 + 2] = q2; }
    __syncthreads();
    q0 = sred[0] + sred[3] + sred[6] + sred[9];
    q1 = sred[1] + sred[4] + sred[7] + sred[10];
    q2 = sred[2] + sred[5] + sred[8] + sred[11];

    const float sb0 = S_b[0];
    const float* av = aind + b * N_;
    const float* bv2 = bind + b * N_;
    const float* dv = Dv + b * N_;
    const float* sv = speak_all + (size_t)b * 3 * N_;
    for (int n = tid; n < N_; n += 256)
        sscore[n] = dv[n] * (av[n] * q0 + bv2[n] * q1 + sv[n] * q2) + sb0;
    __syncthreads();

    int r0;
    {
        float best = -INFINITY; int bi = N_;
        for (int n = tid; n < N_; n += 256) {
            const float s = sscore[n];
            if (s > best || (s == best && n < bi)) { best = s; bi = n; }
        }
#pragma unroll
        for (int off = 32; off > 0; off >>= 1) {
            const float ov = __shfl_xor(best, off); const int oi = __shfl_xor(bi, off);
            if (ov > best || (ov == best && oi < bi)) { best = ov; bi = oi; }
        }
        if (lane == 0) { sred[wv] = best; sidx[wv] = bi; }
        __syncthreads();
        float v = -INFINITY; int i = N_;
        for (int k = 0; k < 4; ++k)
            if (sred[k] > v || (sred[k] == v && sidx[k] < i)) { v = sred[k]; i = sidx[k]; }
        r0 = i;
    }
    __syncthreads();
    int r1;
    {
        float best = -INFINITY; int bi = N_;
        for (int n = tid; n < N_; n += 256) {
            if (n == r0) continue;
            const float s = sscore[n];
            if (s > best || (s == best && n < bi)) { best = s; bi = n; }
        }
#pragma unroll
        for (int off = 32; off > 0; off >>= 1) {
            const float ov = __shfl_xor(best, off); const int oi = __shfl_xor(bi, off);
            if (ov > best || (ov == best && oi < bi)) { best = ov; bi = oi; }
        }
        if (lane == 0) { sred[wv] = best; sidx[wv] = bi; }
        __syncthreads();
        float v = -INFINITY; int i = N_;
        for (int k = 0; k < 4; ++k)
            if (sred[k] > v || (sred[k] == v && sidx[k] < i)) { v = sred[k]; i = sidx[k]; }
        r1 = i;
    }

    float* ob = out + (size_t)b * 2 * H_;
    {
        const float d = dv[r0], wa = av[r0], wbn = bv2[r0], wsv = sv[r0];
        for (int j = tid; j < H_; j += 256)
            ob[j] = d * (wa * sKh[j] + wbn * sKh[H_ + j] + wsv * sKh[2 * H_ + j]);
    }
    {
        const float d = dv[r1], wa = av[r1], wbn = bv2[r1], wsv = sv[r1];
        for (int j = tid; j < H_; j += 256)
            ob[H_ + j] = d * (wa * sKh[j] + wbn * sKh[H_ + j] + wsv * sKh[2 * H_ + j]);
    }
}

extern "C" void kernel_launch(void* const* d_in, const int* in_sizes, int n_in,
                              void* d_out, int out_size, void* d_ws, size_t ws_size,
                              hipStream_t stream)
{
    const float* h         = (const float*)d_in[0];   // (B,N,H)
    const float* att       = (const float*)d_in[1];   // (B,1,N,N)
    const int*   a_idx     = (const int*)d_in[2];     // (B,8)
    const int*   b_idx     = (const int*)d_in[3];     // (B,8)
    const float* speak_all = (const float*)d_in[5];   // (B,3,N)
    const float* W_w       = (const float*)d_in[6];   // (1,H)
    const float* W_b       = (const float*)d_in[7];   // (1,)
    const float* S_w       = (const float*)d_in[8];   // (1,H)
    const float* S_b       = (const float*)d_in[9];   // (1,)
    float* out = (float*)d_out;

    float* ws      = (float*)d_ws;
    float* aind    = ws;                              // B*N
    float* bind    = aind + B_ * N_;                  // B*N
    float* Dv      = bind + B_ * N_;                  // B*N
    float* De      = Dv + B_ * N_;                    // 96, pad 128
    int*   npadArr = (int*)(De + 128);                // 32, pad 128
    float4* comp   = (float4*)(De + 256);             // B*CMAX_ float4
    float* MZ      = De + 256 + B_ * CMAX_ * 4;       // B*CH_*8
    float* UGpart  = MZ + B_ * CH_ * 8;               // B*CH_*6*H

    k1_ind<<<B_, 1024, 0, stream>>>(att, a_idx, b_idx, speak_all, aind, bind,
                                    Dv, De, comp, npadArr);
    kBC2<<<dim3(CH_, B_), 256, 0, stream>>>(att, comp, npadArr, h, Dv, UGpart, MZ);
    k45_fin<<<B_, 256, 0, stream>>>(UGpart, MZ, De, Dv, aind, bind, speak_all,
                                    W_w, W_b, S_w, S_b, out);
}

// Round 10
// 78.941 us; speedup vs baseline: 6.2303x; 1.0145x over previous
//
#include <hip/hip_runtime.h>
#include <math.h>

#define B_ 32
#define N_ 1024
#define H_ 768
#define A_ 8
#define TOPK_ 20
#define CH_ 32
#define CMAX_ 1280

__device__ __forceinline__ float wsum(float x) {
#pragma unroll
    for (int off = 32; off > 0; off >>= 1) x += __shfl_xor(x, off);
    return x;
}

// ---------------------------------------------------------------------------
// K1: top-20 indicators, Dv, De, compacted active-row list (padded to x128).
// grid=B, block=1024.
// ---------------------------------------------------------------------------
__global__ __launch_bounds__(1024) void k1_ind(
    const float* __restrict__ att, const int* __restrict__ a_idx,
    const int* __restrict__ b_idx, const float* __restrict__ speak_all,
    float* __restrict__ aind, float* __restrict__ bind,
    float* __restrict__ Dv, float* __restrict__ De,
    float4* __restrict__ comp, int* __restrict__ npadArr)
{
    const int b = blockIdx.x;
    const int tid = threadIdx.x;
    const int w = tid >> 6, lane = tid & 63;
    __shared__ float s_ind[2][N_];
    __shared__ float s_red[3][16];
    __shared__ int wcnt[16];
    __shared__ int woff[17];

    s_ind[0][tid] = 0.f;
    s_ind[1][tid] = 0.f;
    __syncthreads();

    const int which = w >> 3;
    const int r = w & 7;
    const int idx = which ? b_idx[b * A_ + r] : a_idx[b * A_ + r];
    if (idx != 0) {   // mask = (idx != 0)
        const float* row = att + ((size_t)b * N_ + idx) * N_;
        float v[16];
#pragma unroll
        for (int k = 0; k < 16; ++k) v[k] = row[(k << 6) + lane];
        float* dst = s_ind[which];
        for (int t2 = 0; t2 < TOPK_; ++t2) {
            float bv = v[0]; int bk = 0;
#pragma unroll
            for (int k = 1; k < 16; ++k)
                if (v[k] > bv) { bv = v[k]; bk = k; }   // lower col wins ties
            int bc = (bk << 6) + lane;
#pragma unroll
            for (int off = 32; off > 0; off >>= 1) {
                float ov = __shfl_xor(bv, off);
                int oc = __shfl_xor(bc, off);
                if (ov > bv || (ov == bv && oc < bc)) { bv = ov; bc = oc; }
            }
            if (lane == 0) dst[bc] = 1.f;   // benign same-value races
            if (lane == (bc & 63)) v[bc >> 6] = -INFINITY;
        }
    }
    __syncthreads();

    const float sa = s_ind[0][tid], sb = s_ind[1][tid];
    const float ss = speak_all[(size_t)b * 3 * N_ + tid];
    aind[b * N_ + tid] = sa;
    bind[b * N_ + tid] = sb;
    Dv[b * N_ + tid] = 1.f / sqrtf(sa + sb + ss + 1.f);

    float p[3] = {sa, sb, ss};
#pragma unroll
    for (int e = 0; e < 3; ++e) {
        float x = wsum(p[e]);
        if (lane == 0) s_red[e][w] = x;
    }

    const bool act = (sa + sb + ss) > 0.f;
    const unsigned long long m = __ballot(act);
    const int wrank = (int)__popcll(m & ((1ull << lane) - 1ull));
    if (lane == 0) wcnt[w] = (int)__popcll(m);
    __syncthreads();
    if (tid == 0) {
        int s = 0;
        for (int i = 0; i < 16; ++i) { woff[i] = s; s += wcnt[i]; }
        woff[16] = s;
        npadArr[b] = (s + 127) & ~127;
    }
    if (tid < 3) {
        float s = 0.f;
        for (int i = 0; i < 16; ++i) s += s_red[tid][i];
        De[b * 3 + tid] = 1.f / sqrtf(s);
    }
    __syncthreads();
    const int nact = woff[16];
    const int npad = (nact + 127) & ~127;
    if (act)
        comp[(size_t)b * CMAX_ + woff[w] + wrank] = make_float4(__int_as_float(tid), sa, sb, ss);
    for (int i = nact + tid; i < npad; i += 1024)
        comp[(size_t)b * CMAX_ + i] = make_float4(__int_as_float(0), 0.f, 0.f, 0.f);
}

// ---------------------------------------------------------------------------
// kBC3: fused Hyper-slice + online-softmax U/G partials.  grid=(32,B),
// block=384 (6 waves), launch_bounds(384,6): VGPR<=~85, ~4 blocks/CU,
// 24 waves/CU.  Phase C uses float2/thread (12 accumulators) so unroll-8
// keeps 8 loads in flight within the register budget.  In-wave shfl
// butterfly replaces the big LDS reduce (LDS ~20KB).
// ---------------------------------------------------------------------------
__global__ __launch_bounds__(384, 6) void kBC3(
    const float* __restrict__ att, const float4* __restrict__ comp,
    const int* __restrict__ npadArr, const float* __restrict__ h,
    const float* __restrict__ Dv,
    float* __restrict__ UGpart, float* __restrict__ MZ)
{
    const int b = blockIdx.y, chunk = blockIdx.x;
    const int n0 = chunk * 32;
    const int t = threadIdx.x;
    const int wv = t >> 6, lane = t & 63;
    __shared__ float4 scomp[1024];     // 16 KB
    __shared__ float wred[6][8][13];   // 2.5 KB (stride-13 pad)
    __shared__ float sHy[96];
    __shared__ float sw6[192];
    __shared__ float smz[8];

    // ---- load compacted row list ----
    const int npad = npadArr[b];
    for (int i = t; i < npad; i += 384) scomp[i] = comp[(size_t)b * CMAX_ + i];
    __syncthreads();

    // ---- phase B: Hyper slice for cols n0..n0+31 (48 row-slices x 8 col-quads)
    const int cx = t & 7, ig = t >> 3;   // ig in [0,48)
    {
        float a0x=0,a0y=0,a0z=0,a0w=0, a1x=0,a1y=0,a1z=0,a1w=0, a2x=0,a2y=0,a2z=0,a2w=0;
        const float* bb = att + (size_t)b * N_ * N_ + n0 + cx * 4;
#pragma unroll 4
        for (int i = ig; i < npad; i += 48) {
            const float4 c = scomp[i];
            const float4 v = *(const float4*)(bb + (size_t)__float_as_int(c.x) * N_);
            a0x += c.y*v.x; a0y += c.y*v.y; a0z += c.y*v.z; a0w += c.y*v.w;
            a1x += c.z*v.x; a1y += c.z*v.y; a1z += c.z*v.z; a1w += c.z*v.w;
            a2x += c.w*v.x; a2y += c.w*v.y; a2z += c.w*v.z; a2w += c.w*v.w;
        }
        float a[12] = {a0x,a0y,a0z,a0w, a1x,a1y,a1z,a1w, a2x,a2y,a2z,a2w};
        // in-wave butterfly over the 8 ig-slices living in this wave
#pragma unroll
        for (int k = 0; k < 12; ++k) {
            float x = a[k];
            x += __shfl_xor(x, 8);
            x += __shfl_xor(x, 16);
            x += __shfl_xor(x, 32);
            a[k] = x;
        }
        if (lane < 8) {   // lane == cx for the ig-slice rep
#pragma unroll
            for (int k = 0; k < 12; ++k) wred[wv][lane][k] = a[k];
        }
    }
    __syncthreads();
    if (t < 96) {   // 8 col-quads x 12 components
        const int cx2 = t / 12, k = t % 12;
        float s = 0.f;
#pragma unroll
        for (int w2 = 0; w2 < 6; ++w2) s += wred[w2][cx2][k];
        sHy[(k >> 2) * 32 + cx2 * 4 + (k & 3)] = s;
    }
    __syncthreads();

    // ---- local softmax stats over this chunk's 32 values (waves 0-2) ----
    if (wv < 3) {
        const float val = (lane < 32) ? sHy[wv * 32 + lane] : -INFINITY;
        float m = val;
#pragma unroll
        for (int off = 32; off > 0; off >>= 1) m = fmaxf(m, __shfl_xor(m, off));
        float z = (lane < 32) ? __expf(val - m) : 0.f;
        z = wsum(z);
        if (lane == 0) { smz[wv] = m; smz[4 + wv] = z; }
    }
    __syncthreads();
    if (t < 96) {
        const int e = t >> 5, r = t & 31;
        const float Hv = sHy[e * 32 + r];
        sw6[e * 32 + r] = __expf(Hv - smz[e]);          // unnormalized weight
        sw6[96 + e * 32 + r] = Hv * Dv[b * N_ + n0 + r];
    }
    if (t < 3) {
        MZ[(size_t)(b * CH_ + chunk) * 8 + t]     = smz[t];
        MZ[(size_t)(b * CH_ + chunk) * 8 + 4 + t] = smz[4 + t];
    }
    __syncthreads();

    // ---- phase C: stream h rows n0..n0+31; 384 threads x float2 ----
    {
        float u00=0,u01=0, u10=0,u11=0, u20=0,u21=0;
        float g00=0,g01=0, g10=0,g11=0, g20=0,g21=0;
        const float* base = h + (size_t)b * N_ * H_ + (size_t)n0 * H_ + t * 2;
#pragma unroll 8
        for (int r = 0; r < 32; ++r) {
            const float2 v = *(const float2*)(base + (size_t)r * H_);
            const float w0 = sw6[r], w1 = sw6[32 + r], w2 = sw6[64 + r];
            const float g0 = sw6[96 + r], g1 = sw6[128 + r], g2 = sw6[160 + r];
            u00 += w0*v.x; u01 += w0*v.y;
            u10 += w1*v.x; u11 += w1*v.y;
            u20 += w2*v.x; u21 += w2*v.y;
            g00 += g0*v.x; g01 += g0*v.y;
            g10 += g1*v.x; g11 += g1*v.y;
            g20 += g2*v.x; g21 += g2*v.y;
        }
        float* up = UGpart + (size_t)(b * CH_ + chunk) * 6 * H_ + t * 2;
        *(float2*)(up)          = make_float2(u00, u01);
        *(float2*)(up + H_)     = make_float2(u10, u11);
        *(float2*)(up + 2*H_)   = make_float2(u20, u21);
        *(float2*)(up + 3*H_)   = make_float2(g00, g01);
        *(float2*)(up + 4*H_)   = make_float2(g10, g11);
        *(float2*)(up + 5*H_)   = make_float2(g20, g21);
    }
}

// ---------------------------------------------------------------------------
// K45: combine online-softmax partials, then finalize.  grid=B, block=512.
// 4-deep chunk ILP in the reduce for latency hiding.
// ---------------------------------------------------------------------------
#define K45T_ 512
__global__ __launch_bounds__(K45T_) void k45_fin(
    const float* __restrict__ UGpart, const float* __restrict__ MZ,
    const float* __restrict__ De, const float* __restrict__ Dv,
    const float* __restrict__ aind, const float* __restrict__ bind,
    const float* __restrict__ speak_all,
    const float* __restrict__ W_w, const float* __restrict__ W_b,
    const float* __restrict__ S_w, const float* __restrict__ S_b,
    float* __restrict__ out)
{
    const int b = blockIdx.x, tid = threadIdx.x;
    const int lane = tid & 63, wv = tid >> 6;   // 8 waves
    __shared__ float sUG[6 * H_];
    __shared__ float sKh[3 * H_];
    __shared__ float sscore[N_];
    __shared__ float sMZ[256];
    __shared__ float sscale[CH_ * 4];
    __shared__ float siZ[4];
    __shared__ float sred[24];
    __shared__ float sbest[8];
    __shared__ int sidx[8];

    if (tid < CH_ * 8) sMZ[tid] = MZ[(size_t)b * CH_ * 8 + tid];
    __syncthreads();
    if (tid < 3) {
        float m = -INFINITY;
        for (int c = 0; c < CH_; ++c) m = fmaxf(m, sMZ[c * 8 + tid]);
        float Z = 0.f;
        for (int c = 0; c < CH_; ++c) {
            const float sc = __expf(sMZ[c * 8 + tid] - m);
            sscale[c * 4 + tid] = sc;
            Z += sc * sMZ[c * 8 + 4 + tid];
        }
        siZ[tid] = 1.f / Z;
    }
    __syncthreads();

    // reduce 32 chunks: U scaled, G plain; 4-deep ILP
    {
        const float* p = UGpart + (size_t)b * CH_ * 6 * H_;
        for (int slot = tid; slot < 1152; slot += K45T_) {
            const int s = slot / 192;          // 0..5
            const int off = slot * 4;
            float4 a0 = make_float4(0,0,0,0), a1 = make_float4(0,0,0,0);
            float4 a2 = make_float4(0,0,0,0), a3 = make_float4(0,0,0,0);
            if (s < 3) {
#pragma unroll
                for (int c = 0; c < CH_; c += 4) {
                    const float w0 = sscale[(c+0) * 4 + s];
                    const float w1 = sscale[(c+1) * 4 + s];
                    const float w2 = sscale[(c+2) * 4 + s];
                    const float w3 = sscale[(c+3) * 4 + s];
                    const float4 v0 = *(const float4*)(p + (size_t)(c+0) * 6 * H_ + off);
                    const float4 v1 = *(const float4*)(p + (size_t)(c+1) * 6 * H_ + off);
                    const float4 v2 = *(const float4*)(p + (size_t)(c+2) * 6 * H_ + off);
                    const float4 v3 = *(const float4*)(p + (size_t)(c+3) * 6 * H_ + off);
                    a0.x += w0*v0.x; a0.y += w0*v0.y; a0.z += w0*v0.z; a0.w += w0*v0.w;
                    a1.x += w1*v1.x; a1.y += w1*v1.y; a1.z += w1*v1.z; a1.w += w1*v1.w;
                    a2.x += w2*v2.x; a2.y += w2*v2.y; a2.z += w2*v2.z; a2.w += w2*v2.w;
                    a3.x += w3*v3.x; a3.y += w3*v3.y; a3.z += w3*v3.z; a3.w += w3*v3.w;
                }
            } else {
#pragma unroll
                for (int c = 0; c < CH_; c += 4) {
                    const float4 v0 = *(const float4*)(p + (size_t)(c+0) * 6 * H_ + off);
                    const float4 v1 = *(const float4*)(p + (size_t)(c+1) * 6 * H_ + off);
                    const float4 v2 = *(const float4*)(p + (size_t)(c+2) * 6 * H_ + off);
                    const float4 v3 = *(const float4*)(p + (size_t)(c+3) * 6 * H_ + off);
                    a0.x += v0.x; a0.y += v0.y; a0.z += v0.z; a0.w += v0.w;
                    a1.x += v1.x; a1.y += v1.y; a1.z += v1.z; a1.w += v1.w;
                    a2.x += v2.x; a2.y += v2.y; a2.z += v2.z; a2.w += v2.w;
                    a3.x += v3.x; a3.y += v3.y; a3.z += v3.z; a3.w += v3.w;
                }
            }
            sUG[off + 0] = a0.x + a1.x + a2.x + a3.x;
            sUG[off + 1] = a0.y + a1.y + a2.y + a3.y;
            sUG[off + 2] = a0.z + a1.z + a2.z + a3.z;
            sUG[off + 3] = a0.w + a1.w + a2.w + a3.w;
        }
    }
    __syncthreads();

    const float* Ub = sUG;            // unnormalized exp-weighted sums
    const float* Gb = sUG + 3 * H_;   // exact

    float p0 = 0.f, p1 = 0.f, p2 = 0.f;
    for (int j = tid; j < H_; j += K45T_) {
        const float ww = W_w[j];
        p0 += Ub[j] * ww; p1 += Ub[H_ + j] * ww; p2 += Ub[2 * H_ + j] * ww;
    }
    p0 = wsum(p0); p1 = wsum(p1); p2 = wsum(p2);
    if (lane == 0) { sred[wv * 3 + 0] = p0; sred[wv * 3 + 1] = p1; sred[wv * 3 + 2] = p2; }
    __syncthreads();
    float l0 = 0.f, l1 = 0.f, l2 = 0.f;
    for (int k = 0; k < 8; ++k) { l0 += sred[k * 3]; l1 += sred[k * 3 + 1]; l2 += sred[k * 3 + 2]; }
    const float wb = W_b[0];
    l0 = l0 * siZ[0] + wb; l1 = l1 * siZ[1] + wb; l2 = l2 * siZ[2] + wb;
    const float mx = fmaxf(l0, fmaxf(l1, l2));
    const float e0 = expf(l0 - mx), e1 = expf(l1 - mx), e2 = expf(l2 - mx);
    const float inv = 1.f / (e0 + e1 + e2);
    const float wd0 = e0 * inv * De[b * 3 + 0];
    const float wd1 = e1 * inv * De[b * 3 + 1];
    const float wd2 = e2 * inv * De[b * 3 + 2];
    __syncthreads();

    for (int j = tid; j < H_; j += K45T_) {
        sKh[j]          = wd0 * Gb[j];
        sKh[H_ + j]     = wd1 * Gb[H_ + j];
        sKh[2 * H_ + j] = wd2 * Gb[2 * H_ + j];
    }
    __syncthreads();

    float q0 = 0.f, q1 = 0.f, q2 = 0.f;
    for (int j = tid; j < H_; j += K45T_) {
        const float sw2 = S_w[j];
        q0 += sKh[j] * sw2; q1 += sKh[H_ + j] * sw2; q2 += sKh[2 * H_ + j] * sw2;
    }
    q0 = wsum(q0); q1 = wsum(q1); q2 = wsum(q2);
    if (lane == 0) { sred[wv * 3 + 0] = q0; sred[wv * 3 + 1] = q1; sred[wv * 3 + 2] = q2; }
    __syncthreads();
    q0 = 0.f; q1 = 0.f; q2 = 0.f;
    for (int k = 0; k < 8; ++k) { q0 += sred[k * 3]; q1 += sred[k * 3 + 1]; q2 += sred[k * 3 + 2]; }

    const float sb0 = S_b[0];
    const float* av = aind + b * N_;
    const float* bv2 = bind + b * N_;
    const float* dv = Dv + b * N_;
    const float* sv = speak_all + (size_t)b * 3 * N_;
    for (int n = tid; n < N_; n += K45T_)
        sscore[n] = dv[n] * (av[n] * q0 + bv2[n] * q1 + sv[n] * q2) + sb0;
    __syncthreads();

    int r0;
    {
        float best = -INFINITY; int bi = N_;
        for (int n = tid; n < N_; n += K45T_) {
            const float s = sscore[n];
            if (s > best || (s == best && n < bi)) { best = s; bi = n; }
        }
#pragma unroll
        for (int off = 32; off > 0; off >>= 1) {
            const float ov = __shfl_xor(best, off); const int oi = __shfl_xor(bi, off);
            if (ov > best || (ov == best && oi < bi)) { best = ov; bi = oi; }
        }
        if (lane == 0) { sbest[wv] = best; sidx[wv] = bi; }
        __syncthreads();
        float v = -INFINITY; int i = N_;
        for (int k = 0; k < 8; ++k)
            if (sbest[k] > v || (sbest[k] == v && sidx[k] < i)) { v = sbest[k]; i = sidx[k]; }
        r0 = i;
    }
    __syncthreads();
    int r1;
    {
        float best = -INFINITY; int bi = N_;
        for (int n = tid; n < N_; n += K45T_) {
            if (n == r0) continue;
            const float s = sscore[n];
            if (s > best || (s == best && n < bi)) { best = s; bi = n; }
        }
#pragma unroll
        for (int off = 32; off > 0; off >>= 1) {
            const float ov = __shfl_xor(best, off); const int oi = __shfl_xor(bi, off);
            if (ov > best || (ov == best && oi < bi)) { best = ov; bi = oi; }
        }
        if (lane == 0) { sbest[wv] = best; sidx[wv] = bi; }
        __syncthreads();
        float v = -INFINITY; int i = N_;
        for (int k = 0; k < 8; ++k)
            if (sbest[k] > v || (sbest[k] == v && sidx[k] < i)) { v = sbest[k]; i = sidx[k]; }
        r1 = i;
    }

    float* ob = out + (size_t)b * 2 * H_;
    {
        const float d = dv[r0], wa = av[r0], wbn = bv2[r0], wsv = sv[r0];
        for (int j = tid; j < H_; j += K45T_)
            ob[j] = d * (wa * sKh[j] + wbn * sKh[H_ + j] + wsv * sKh[2 * H_ + j]);
    }
    {
        const float d = dv[r1], wa = av[r1], wbn = bv2[r1], wsv = sv[r1];
        for (int j = tid; j < H_; j += K45T_)
            ob[H_ + j] = d * (wa * sKh[j] + wbn * sKh[H_ + j] + wsv * sKh[2 * H_ + j]);
    }
}

extern "C" void kernel_launch(void* const* d_in, const int* in_sizes, int n_in,
                              void* d_out, int out_size, void* d_ws, size_t ws_size,
                              hipStream_t stream)
{
    const float* h         = (const float*)d_in[0];   // (B,N,H)
    const float* att       = (const float*)d_in[1];   // (B,1,N,N)
    const int*   a_idx     = (const int*)d_in[2];     // (B,8)
    const int*   b_idx     = (const int*)d_in[3];     // (B,8)
    const float* speak_all = (const float*)d_in[5];   // (B,3,N)
    const float* W_w       = (const float*)d_in[6];   // (1,H)
    const float* W_b       = (const float*)d_in[7];   // (1,)
    const float* S_w       = (const float*)d_in[8];   // (1,H)
    const float* S_b       = (const float*)d_in[9];   // (1,)
    float* out = (float*)d_out;

    float* ws      = (float*)d_ws;
    float* aind    = ws;                              // B*N
    float* bind    = aind + B_ * N_;                  // B*N
    float* Dv      = bind + B_ * N_;                  // B*N
    float* De      = Dv + B_ * N_;                    // 96, pad 128
    int*   npadArr = (int*)(De + 128);                // 32, pad 128
    float4* comp   = (float4*)(De + 256);             // B*CMAX_ float4
    float* MZ      = De + 256 + B_ * CMAX_ * 4;       // B*CH_*8
    float* UGpart  = MZ + B_ * CH_ * 8;               // B*CH_*6*H

    k1_ind<<<B_, 1024, 0, stream>>>(att, a_idx, b_idx, speak_all, aind, bind,
                                    Dv, De, comp, npadArr);
    kBC3<<<dim3(CH_, B_), 384, 0, stream>>>(att, comp, npadArr, h, Dv, UGpart, MZ);
    k45_fin<<<B_, K45T_, 0, stream>>>(UGpart, MZ, De, Dv, aind, bind, speak_all,
                                      W_w, W_b, S_w, S_b, out);
}

// Round 11
// 74.923 us; speedup vs baseline: 6.5643x; 1.0536x over previous
//
#include <hip/hip_runtime.h>
#include <math.h>

#define B_ 32
#define N_ 1024
#define H_ 768
#define A_ 8
#define TOPK_ 20
#define CH_ 16      // 16 chunks x 64 rows
#define CMAX_ 1056  // max npad (1024 rounded up to 24-multiple)

typedef float f32x4 __attribute__((ext_vector_type(4)));
typedef float f32x2 __attribute__((ext_vector_type(2)));

__device__ __forceinline__ float wsum(float x) {
#pragma unroll
    for (int off = 32; off > 0; off >>= 1) x += __shfl_xor(x, off);
    return x;
}

// ---------------------------------------------------------------------------
// K1: top-20 indicators, Dv, De, compacted active-row list (padded to x24).
// grid=B, block=1024.
// ---------------------------------------------------------------------------
__global__ __launch_bounds__(1024) void k1_ind(
    const float* __restrict__ att, const int* __restrict__ a_idx,
    const int* __restrict__ b_idx, const float* __restrict__ speak_all,
    float* __restrict__ aind, float* __restrict__ bind,
    float* __restrict__ Dv, float* __restrict__ De,
    float4* __restrict__ comp, int* __restrict__ npadArr)
{
    const int b = blockIdx.x;
    const int tid = threadIdx.x;
    const int w = tid >> 6, lane = tid & 63;
    __shared__ float s_ind[2][N_];
    __shared__ float s_red[3][16];
    __shared__ int wcnt[16];
    __shared__ int woff[17];

    s_ind[0][tid] = 0.f;
    s_ind[1][tid] = 0.f;
    __syncthreads();

    const int which = w >> 3;
    const int r = w & 7;
    const int idx = which ? b_idx[b * A_ + r] : a_idx[b * A_ + r];
    if (idx != 0) {   // mask = (idx != 0)
        const float* row = att + ((size_t)b * N_ + idx) * N_;
        float v[16];
#pragma unroll
        for (int k = 0; k < 16; ++k) v[k] = row[(k << 6) + lane];
        float* dst = s_ind[which];
        for (int t2 = 0; t2 < TOPK_; ++t2) {
            float bv = v[0]; int bk = 0;
#pragma unroll
            for (int k = 1; k < 16; ++k)
                if (v[k] > bv) { bv = v[k]; bk = k; }   // lower col wins ties
            int bc = (bk << 6) + lane;
#pragma unroll
            for (int off = 32; off > 0; off >>= 1) {
                float ov = __shfl_xor(bv, off);
                int oc = __shfl_xor(bc, off);
                if (ov > bv || (ov == bv && oc < bc)) { bv = ov; bc = oc; }
            }
            if (lane == 0) dst[bc] = 1.f;   // benign same-value races
            if (lane == (bc & 63)) v[bc >> 6] = -INFINITY;
        }
    }
    __syncthreads();

    const float sa = s_ind[0][tid], sb = s_ind[1][tid];
    const float ss = speak_all[(size_t)b * 3 * N_ + tid];
    aind[b * N_ + tid] = sa;
    bind[b * N_ + tid] = sb;
    Dv[b * N_ + tid] = 1.f / sqrtf(sa + sb + ss + 1.f);

    float p[3] = {sa, sb, ss};
#pragma unroll
    for (int e = 0; e < 3; ++e) {
        float x = wsum(p[e]);
        if (lane == 0) s_red[e][w] = x;
    }

    const bool act = (sa + sb + ss) > 0.f;
    const unsigned long long m = __ballot(act);
    const int wrank = (int)__popcll(m & ((1ull << lane) - 1ull));
    if (lane == 0) wcnt[w] = (int)__popcll(m);
    __syncthreads();
    if (tid == 0) {
        int s = 0;
        for (int i = 0; i < 16; ++i) { woff[i] = s; s += wcnt[i]; }
        woff[16] = s;
        npadArr[b] = (s + 23) / 24 * 24;
    }
    if (tid < 3) {
        float s = 0.f;
        for (int i = 0; i < 16; ++i) s += s_red[tid][i];
        De[b * 3 + tid] = 1.f / sqrtf(s);
    }
    __syncthreads();
    const int nact = woff[16];
    const int npad = (nact + 23) / 24 * 24;
    if (act)
        comp[(size_t)b * CMAX_ + woff[w] + wrank] = make_float4(__int_as_float(tid), sa, sb, ss);
    for (int i = nact + tid; i < npad; i += 1024)
        comp[(size_t)b * CMAX_ + i] = make_float4(__int_as_float(0), 0.f, 0.f, 0.f);
}

// ---------------------------------------------------------------------------
// kBC4: fused Hyper-slice + online-softmax U/G partials over 64-row chunks.
// grid=(16,B), block=384, launch_bounds(384,6).  Non-temporal loads on the
// att/h streams (stream-once data).  24-granular row padding.
// ---------------------------------------------------------------------------
__global__ __launch_bounds__(384, 6) void kBC4(
    const float* __restrict__ att, const float4* __restrict__ comp,
    const int* __restrict__ npadArr, const float* __restrict__ h,
    const float* __restrict__ Dv,
    float* __restrict__ UGpart, float* __restrict__ MZ)
{
    const int b = blockIdx.y, chunk = blockIdx.x;
    const int n0 = chunk * 64;
    const int t = threadIdx.x;
    const int wv = t >> 6, lane = t & 63;
    __shared__ float4 scomp[CMAX_];     // 16.9 KB
    __shared__ float wred[6][16][13];   // 5 KB (stride-13 pad)
    __shared__ float sHy[192];          // 3 edges x 64 cols
    __shared__ float sw6[384];          // w[3][64] then gg[3][64]
    __shared__ float smz[8];

    // ---- load compacted row list ----
    const int npad = npadArr[b];
    for (int i = t; i < npad; i += 384) scomp[i] = comp[(size_t)b * CMAX_ + i];
    __syncthreads();

    // ---- phase B: Hyper slice for cols n0..n0+63 (24 row-slices x 16 col-quads)
    const int cx = t & 15, ig = t >> 4;   // cx in [0,16), ig in [0,24)
    {
        float a0x=0,a0y=0,a0z=0,a0w=0, a1x=0,a1y=0,a1z=0,a1w=0, a2x=0,a2y=0,a2z=0,a2w=0;
        const float* bb = att + (size_t)b * N_ * N_ + n0 + cx * 4;
#pragma unroll 4
        for (int i = ig; i < npad; i += 24) {
            const float4 c = scomp[i];
            const f32x4 v = __builtin_nontemporal_load(
                (const f32x4*)(bb + (size_t)__float_as_int(c.x) * N_));
            a0x += c.y*v.x; a0y += c.y*v.y; a0z += c.y*v.z; a0w += c.y*v.w;
            a1x += c.z*v.x; a1y += c.z*v.y; a1z += c.z*v.z; a1w += c.z*v.w;
            a2x += c.w*v.x; a2y += c.w*v.y; a2z += c.w*v.z; a2w += c.w*v.w;
        }
        float a[12] = {a0x,a0y,a0z,a0w, a1x,a1y,a1z,a1w, a2x,a2y,a2z,a2w};
        // butterfly over the 4 ig-slices living in this wave (lane bits 4,5)
#pragma unroll
        for (int k = 0; k < 12; ++k) {
            float x = a[k];
            x += __shfl_xor(x, 16);
            x += __shfl_xor(x, 32);
            a[k] = x;
        }
        if (lane < 16) {   // lane == cx for slice 0
#pragma unroll
            for (int k = 0; k < 12; ++k) wred[wv][lane][k] = a[k];
        }
    }
    __syncthreads();
    if (t < 192) {   // 16 col-quads x 12 components
        const int quad = t / 12, k = t % 12;
        float s = 0.f;
#pragma unroll
        for (int w2 = 0; w2 < 6; ++w2) s += wred[w2][quad][k];
        sHy[(k >> 2) * 64 + quad * 4 + (k & 3)] = s;
    }
    __syncthreads();

    // ---- local softmax stats over this chunk's 64 values (waves 0-2) ----
    if (wv < 3) {
        const float val = sHy[wv * 64 + lane];
        float m = val;
#pragma unroll
        for (int off = 32; off > 0; off >>= 1) m = fmaxf(m, __shfl_xor(m, off));
        float z = __expf(val - m);
        z = wsum(z);
        if (lane == 0) { smz[wv] = m; smz[4 + wv] = z; }
    }
    __syncthreads();
    if (t < 192) {
        const int e = t >> 6, r2 = t & 63;
        const float Hv = sHy[e * 64 + r2];
        sw6[e * 64 + r2] = __expf(Hv - smz[e]);              // unnormalized weight
        sw6[192 + e * 64 + r2] = Hv * Dv[b * N_ + n0 + r2];
    }
    if (t < 3) {
        MZ[(size_t)(b * CH_ + chunk) * 8 + t]     = smz[t];
        MZ[(size_t)(b * CH_ + chunk) * 8 + 4 + t] = smz[4 + t];
    }
    __syncthreads();

    // ---- phase C: stream h rows n0..n0+63; 384 threads x float2 ----
    {
        float u00=0,u01=0, u10=0,u11=0, u20=0,u21=0;
        float g00=0,g01=0, g10=0,g11=0, g20=0,g21=0;
        const float* base = h + (size_t)b * N_ * H_ + (size_t)n0 * H_ + t * 2;
#pragma unroll 8
        for (int r2 = 0; r2 < 64; ++r2) {
            const f32x2 v = __builtin_nontemporal_load(
                (const f32x2*)(base + (size_t)r2 * H_));
            const float w0 = sw6[r2], w1 = sw6[64 + r2], w2 = sw6[128 + r2];
            const float g0 = sw6[192 + r2], g1 = sw6[256 + r2], g2 = sw6[320 + r2];
            u00 += w0*v.x; u01 += w0*v.y;
            u10 += w1*v.x; u11 += w1*v.y;
            u20 += w2*v.x; u21 += w2*v.y;
            g00 += g0*v.x; g01 += g0*v.y;
            g10 += g1*v.x; g11 += g1*v.y;
            g20 += g2*v.x; g21 += g2*v.y;
        }
        float* up = UGpart + (size_t)(b * CH_ + chunk) * 6 * H_ + t * 2;
        *(float2*)(up)          = make_float2(u00, u01);
        *(float2*)(up + H_)     = make_float2(u10, u11);
        *(float2*)(up + 2*H_)   = make_float2(u20, u21);
        *(float2*)(up + 3*H_)   = make_float2(g00, g01);
        *(float2*)(up + 4*H_)   = make_float2(g10, g11);
        *(float2*)(up + 5*H_)   = make_float2(g20, g21);
    }
}

// ---------------------------------------------------------------------------
// K45: combine online-softmax partials, then finalize.  grid=B, block=512.
// ---------------------------------------------------------------------------
#define K45T_ 512
__global__ __launch_bounds__(K45T_) void k45_fin(
    const float* __restrict__ UGpart, const float* __restrict__ MZ,
    const float* __restrict__ De, const float* __restrict__ Dv,
    const float* __restrict__ aind, const float* __restrict__ bind,
    const float* __restrict__ speak_all,
    const float* __restrict__ W_w, const float* __restrict__ W_b,
    const float* __restrict__ S_w, const float* __restrict__ S_b,
    float* __restrict__ out)
{
    const int b = blockIdx.x, tid = threadIdx.x;
    const int lane = tid & 63, wv = tid >> 6;   // 8 waves
    __shared__ float sUG[6 * H_];
    __shared__ float sKh[3 * H_];
    __shared__ float sscore[N_];
    __shared__ float sMZ[CH_ * 8];
    __shared__ float sscale[CH_ * 4];
    __shared__ float siZ[4];
    __shared__ float sred[24];
    __shared__ float sbest[8];
    __shared__ int sidx[8];

    if (tid < CH_ * 8) sMZ[tid] = MZ[(size_t)b * CH_ * 8 + tid];
    __syncthreads();
    if (tid < 3) {
        float m = -INFINITY;
        for (int c = 0; c < CH_; ++c) m = fmaxf(m, sMZ[c * 8 + tid]);
        float Z = 0.f;
        for (int c = 0; c < CH_; ++c) {
            const float sc = __expf(sMZ[c * 8 + tid] - m);
            sscale[c * 4 + tid] = sc;
            Z += sc * sMZ[c * 8 + 4 + tid];
        }
        siZ[tid] = 1.f / Z;
    }
    __syncthreads();

    // reduce 16 chunks: U scaled, G plain; 4-deep ILP
    {
        const float* p = UGpart + (size_t)b * CH_ * 6 * H_;
        for (int slot = tid; slot < 1152; slot += K45T_) {
            const int s = slot / 192;          // 0..5
            const int off = slot * 4;
            float4 a0 = make_float4(0,0,0,0), a1 = make_float4(0,0,0,0);
            float4 a2 = make_float4(0,0,0,0), a3 = make_float4(0,0,0,0);
            if (s < 3) {
#pragma unroll
                for (int c = 0; c < CH_; c += 4) {
                    const float w0 = sscale[(c+0) * 4 + s];
                    const float w1 = sscale[(c+1) * 4 + s];
                    const float w2 = sscale[(c+2) * 4 + s];
                    const float w3 = sscale[(c+3) * 4 + s];
                    const f32x4 v0 = __builtin_nontemporal_load((const f32x4*)(p + (size_t)(c+0) * 6 * H_ + off));
                    const f32x4 v1 = __builtin_nontemporal_load((const f32x4*)(p + (size_t)(c+1) * 6 * H_ + off));
                    const f32x4 v2 = __builtin_nontemporal_load((const f32x4*)(p + (size_t)(c+2) * 6 * H_ + off));
                    const f32x4 v3 = __builtin_nontemporal_load((const f32x4*)(p + (size_t)(c+3) * 6 * H_ + off));
                    a0.x += w0*v0.x; a0.y += w0*v0.y; a0.z += w0*v0.z; a0.w += w0*v0.w;
                    a1.x += w1*v1.x; a1.y += w1*v1.y; a1.z += w1*v1.z; a1.w += w1*v1.w;
                    a2.x += w2*v2.x; a2.y += w2*v2.y; a2.z += w2*v2.z; a2.w += w2*v2.w;
                    a3.x += w3*v3.x; a3.y += w3*v3.y; a3.z += w3*v3.z; a3.w += w3*v3.w;
                }
            } else {
#pragma unroll
                for (int c = 0; c < CH_; c += 4) {
                    const f32x4 v0 = __builtin_nontemporal_load((const f32x4*)(p + (size_t)(c+0) * 6 * H_ + off));
                    const f32x4 v1 = __builtin_nontemporal_load((const f32x4*)(p + (size_t)(c+1) * 6 * H_ + off));
                    const f32x4 v2 = __builtin_nontemporal_load((const f32x4*)(p + (size_t)(c+2) * 6 * H_ + off));
                    const f32x4 v3 = __builtin_nontemporal_load((const f32x4*)(p + (size_t)(c+3) * 6 * H_ + off));
                    a0.x += v0.x; a0.y += v0.y; a0.z += v0.z; a0.w += v0.w;
                    a1.x += v1.x; a1.y += v1.y; a1.z += v1.z; a1.w += v1.w;
                    a2.x += v2.x; a2.y += v2.y; a2.z += v2.z; a2.w += v2.w;
                    a3.x += v3.x; a3.y += v3.y; a3.z += v3.z; a3.w += v3.w;
                }
            }
            sUG[off + 0] = a0.x + a1.x + a2.x + a3.x;
            sUG[off + 1] = a0.y + a1.y + a2.y + a3.y;
            sUG[off + 2] = a0.z + a1.z + a2.z + a3.z;
            sUG[off + 3] = a0.w + a1.w + a2.w + a3.w;
        }
    }
    __syncthreads();

    const float* Ub = sUG;            // unnormalized exp-weighted sums
    const float* Gb = sUG + 3 * H_;   // exact

    float p0 = 0.f, p1 = 0.f, p2 = 0.f;
    for (int j = tid; j < H_; j += K45T_) {
        const float ww = W_w[j];
        p0 += Ub[j] * ww; p1 += Ub[H_ + j] * ww; p2 += Ub[2 * H_ + j] * ww;
    }
    p0 = wsum(p0); p1 = wsum(p1); p2 = wsum(p2);
    if (lane == 0) { sred[wv * 3 + 0] = p0; sred[wv * 3 + 1] = p1; sred[wv * 3 + 2] = p2; }
    __syncthreads();
    float l0 = 0.f, l1 = 0.f, l2 = 0.f;
    for (int k = 0; k < 8; ++k) { l0 += sred[k * 3]; l1 += sred[k * 3 + 1]; l2 += sred[k * 3 + 2]; }
    const float wb = W_b[0];
    l0 = l0 * siZ[0] + wb; l1 = l1 * siZ[1] + wb; l2 = l2 * siZ[2] + wb;
    const float mx = fmaxf(l0, fmaxf(l1, l2));
    const float e0 = expf(l0 - mx), e1 = expf(l1 - mx), e2 = expf(l2 - mx);
    const float inv = 1.f / (e0 + e1 + e2);
    const float wd0 = e0 * inv * De[b * 3 + 0];
    const float wd1 = e1 * inv * De[b * 3 + 1];
    const float wd2 = e2 * inv * De[b * 3 + 2];
    __syncthreads();

    for (int j = tid; j < H_; j += K45T_) {
        sKh[j]          = wd0 * Gb[j];
        sKh[H_ + j]     = wd1 * Gb[H_ + j];
        sKh[2 * H_ + j] = wd2 * Gb[2 * H_ + j];
    }
    __syncthreads();

    float q0 = 0.f, q1 = 0.f, q2 = 0.f;
    for (int j = tid; j < H_; j += K45T_) {
        const float sw2 = S_w[j];
        q0 += sKh[j] * sw2; q1 += sKh[H_ + j] * sw2; q2 += sKh[2 * H_ + j] * sw2;
    }
    q0 = wsum(q0); q1 = wsum(q1); q2 = wsum(q2);
    if (lane == 0) { sred[wv * 3 + 0] = q0; sred[wv * 3 + 1] = q1; sred[wv * 3 + 2] = q2; }
    __syncthreads();
    q0 = 0.f; q1 = 0.f; q2 = 0.f;
    for (int k = 0; k < 8; ++k) { q0 += sred[k * 3]; q1 += sred[k * 3 + 1]; q2 += sred[k * 3 + 2]; }

    const float sb0 = S_b[0];
    const float* av = aind + b * N_;
    const float* bv2 = bind + b * N_;
    const float* dv = Dv + b * N_;
    const float* sv = speak_all + (size_t)b * 3 * N_;
    for (int n = tid; n < N_; n += K45T_)
        sscore[n] = dv[n] * (av[n] * q0 + bv2[n] * q1 + sv[n] * q2) + sb0;
    __syncthreads();

    int r0;
    {
        float best = -INFINITY; int bi = N_;
        for (int n = tid; n < N_; n += K45T_) {
            const float s = sscore[n];
            if (s > best || (s == best && n < bi)) { best = s; bi = n; }
        }
#pragma unroll
        for (int off = 32; off > 0; off >>= 1) {
            const float ov = __shfl_xor(best, off); const int oi = __shfl_xor(bi, off);
            if (ov > best || (ov == best && oi < bi)) { best = ov; bi = oi; }
        }
        if (lane == 0) { sbest[wv] = best; sidx[wv] = bi; }
        __syncthreads();
        float v = -INFINITY; int i = N_;
        for (int k = 0; k < 8; ++k)
            if (sbest[k] > v || (sbest[k] == v && sidx[k] < i)) { v = sbest[k]; i = sidx[k]; }
        r0 = i;
    }
    __syncthreads();
    int r1;
    {
        float best = -INFINITY; int bi = N_;
        for (int n = tid; n < N_; n += K45T_) {
            if (n == r0) continue;
            const float s = sscore[n];
            if (s > best || (s == best && n < bi)) { best = s; bi = n; }
        }
#pragma unroll
        for (int off = 32; off > 0; off >>= 1) {
            const float ov = __shfl_xor(best, off); const int oi = __shfl_xor(bi, off);
            if (ov > best || (ov == best && oi < bi)) { best = ov; bi = oi; }
        }
        if (lane == 0) { sbest[wv] = best; sidx[wv] = bi; }
        __syncthreads();
        float v = -INFINITY; int i = N_;
        for (int k = 0; k < 8; ++k)
            if (sbest[k] > v || (sbest[k] == v && sidx[k] < i)) { v = sbest[k]; i = sidx[k]; }
        r1 = i;
    }

    float* ob = out + (size_t)b * 2 * H_;
    {
        const float d = dv[r0], wa = av[r0], wbn = bv2[r0], wsv = sv[r0];
        for (int j = tid; j < H_; j += K45T_)
            ob[j] = d * (wa * sKh[j] + wbn * sKh[H_ + j] + wsv * sKh[2 * H_ + j]);
    }
    {
        const float d = dv[r1], wa = av[r1], wbn = bv2[r1], wsv = sv[r1];
        for (int j = tid; j < H_; j += K45T_)
            ob[H_ + j] = d * (wa * sKh[j] + wbn * sKh[H_ + j] + wsv * sKh[2 * H_ + j]);
    }
}

extern "C" void kernel_launch(void* const* d_in, const int* in_sizes, int n_in,
                              void* d_out, int out_size, void* d_ws, size_t ws_size,
                              hipStream_t stream)
{
    const float* h         = (const float*)d_in[0];   // (B,N,H)
    const float* att       = (const float*)d_in[1];   // (B,1,N,N)
    const int*   a_idx     = (const int*)d_in[2];     // (B,8)
    const int*   b_idx     = (const int*)d_in[3];     // (B,8)
    const float* speak_all = (const float*)d_in[5];   // (B,3,N)
    const float* W_w       = (const float*)d_in[6];   // (1,H)
    const float* W_b       = (const float*)d_in[7];   // (1,)
    const float* S_w       = (const float*)d_in[8];   // (1,H)
    const float* S_b       = (const float*)d_in[9];   // (1,)
    float* out = (float*)d_out;

    float* ws      = (float*)d_ws;
    float* aind    = ws;                              // B*N
    float* bind    = aind + B_ * N_;                  // B*N
    float* Dv      = bind + B_ * N_;                  // B*N
    float* De      = Dv + B_ * N_;                    // 96, pad 128
    int*   npadArr = (int*)(De + 128);                // 32, pad 128
    float4* comp   = (float4*)(De + 256);             // B*CMAX_ float4
    float* MZ      = De + 256 + B_ * CMAX_ * 4;       // B*CH_*8
    float* UGpart  = MZ + B_ * CH_ * 8;               // B*CH_*6*H

    k1_ind<<<B_, 1024, 0, stream>>>(att, a_idx, b_idx, speak_all, aind, bind,
                                    Dv, De, comp, npadArr);
    kBC4<<<dim3(CH_, B_), 384, 0, stream>>>(att, comp, npadArr, h, Dv, UGpart, MZ);
    k45_fin<<<B_, K45T_, 0, stream>>>(UGpart, MZ, De, Dv, aind, bind, speak_all,
                                      W_w, W_b, S_w, S_b, out);
}

// Round 12
// 72.961 us; speedup vs baseline: 6.7409x; 1.0269x over previous
//
#include <hip/hip_runtime.h>
#include <math.h>

#define B_ 32
#define N_ 1024
#define H_ 768
#define A_ 8
#define TOPK_ 20
#define CH_ 8       // 8 chunks x 128 rows/cols
#define CMAX_ 1056

typedef float f32x4 __attribute__((ext_vector_type(4)));
typedef float f32x2 __attribute__((ext_vector_type(2)));

__device__ __forceinline__ float wsum(float x) {
#pragma unroll
    for (int off = 32; off > 0; off >>= 1) x += __shfl_xor(x, off);
    return x;
}

// ---------------------------------------------------------------------------
// K1: top-20 indicators, Dv, De, compacted active-row list (padded to x12).
// grid=B, block=1024.
// ---------------------------------------------------------------------------
__global__ __launch_bounds__(1024) void k1_ind(
    const float* __restrict__ att, const int* __restrict__ a_idx,
    const int* __restrict__ b_idx, const float* __restrict__ speak_all,
    float* __restrict__ aind, float* __restrict__ bind,
    float* __restrict__ Dv, float* __restrict__ De,
    float4* __restrict__ comp, int* __restrict__ npadArr)
{
    const int b = blockIdx.x;
    const int tid = threadIdx.x;
    const int w = tid >> 6, lane = tid & 63;
    __shared__ float s_ind[2][N_];
    __shared__ float s_red[3][16];
    __shared__ int wcnt[16];
    __shared__ int woff[17];

    s_ind[0][tid] = 0.f;
    s_ind[1][tid] = 0.f;
    __syncthreads();

    const int which = w >> 3;
    const int r = w & 7;
    const int idx = which ? b_idx[b * A_ + r] : a_idx[b * A_ + r];
    if (idx != 0) {   // mask = (idx != 0)
        const float* row = att + ((size_t)b * N_ + idx) * N_;
        float v[16];
#pragma unroll
        for (int k = 0; k < 16; ++k) v[k] = row[(k << 6) + lane];
        float* dst = s_ind[which];
        for (int t2 = 0; t2 < TOPK_; ++t2) {
            float bv = v[0]; int bk = 0;
#pragma unroll
            for (int k = 1; k < 16; ++k)
                if (v[k] > bv) { bv = v[k]; bk = k; }   // lower col wins ties
            int bc = (bk << 6) + lane;
#pragma unroll
            for (int off = 32; off > 0; off >>= 1) {
                float ov = __shfl_xor(bv, off);
                int oc = __shfl_xor(bc, off);
                if (ov > bv || (ov == bv && oc < bc)) { bv = ov; bc = oc; }
            }
            if (lane == 0) dst[bc] = 1.f;   // benign same-value races
            if (lane == (bc & 63)) v[bc >> 6] = -INFINITY;
        }
    }
    __syncthreads();

    const float sa = s_ind[0][tid], sb = s_ind[1][tid];
    const float ss = speak_all[(size_t)b * 3 * N_ + tid];
    aind[b * N_ + tid] = sa;
    bind[b * N_ + tid] = sb;
    Dv[b * N_ + tid] = 1.f / sqrtf(sa + sb + ss + 1.f);

    float p[3] = {sa, sb, ss};
#pragma unroll
    for (int e = 0; e < 3; ++e) {
        float x = wsum(p[e]);
        if (lane == 0) s_red[e][w] = x;
    }

    const bool act = (sa + sb + ss) > 0.f;
    const unsigned long long m = __ballot(act);
    const int wrank = (int)__popcll(m & ((1ull << lane) - 1ull));
    if (lane == 0) wcnt[w] = (int)__popcll(m);
    __syncthreads();
    if (tid == 0) {
        int s = 0;
        for (int i = 0; i < 16; ++i) { woff[i] = s; s += wcnt[i]; }
        woff[16] = s;
        npadArr[b] = (s + 11) / 12 * 12;
    }
    if (tid < 3) {
        float s = 0.f;
        for (int i = 0; i < 16; ++i) s += s_red[tid][i];
        De[b * 3 + tid] = 1.f / sqrtf(s);
    }
    __syncthreads();
    const int nact = woff[16];
    const int npad = (nact + 11) / 12 * 12;
    if (act)
        comp[(size_t)b * CMAX_ + woff[w] + wrank] = make_float4(__int_as_float(tid), sa, sb, ss);
    for (int i = nact + tid; i < npad; i += 1024)
        comp[(size_t)b * CMAX_ + i] = make_float4(__int_as_float(0), 0.f, 0.f, 0.f);
}

// ---------------------------------------------------------------------------
// kBC5: fused Hyper-slice + online-softmax U/G partials over 128-row chunks.
// grid=(8,B), block=384, launch_bounds(384,6).  nt loads on att/h streams.
// Phase B: 12 row-slices x 32 col-quads.  Phase C: 128 rows x float2/thread.
// ---------------------------------------------------------------------------
__global__ __launch_bounds__(384, 6) void kBC5(
    const float* __restrict__ att, const float4* __restrict__ comp,
    const int* __restrict__ npadArr, const float* __restrict__ h,
    const float* __restrict__ Dv,
    float* __restrict__ UGpart, float* __restrict__ MZ)
{
    const int b = blockIdx.y, chunk = blockIdx.x;
    const int n0 = chunk * 128;
    const int t = threadIdx.x;
    const int wv = t >> 6, lane = t & 63;
    __shared__ float4 scomp[CMAX_];     // 16.9 KB
    __shared__ float wred[6][32][13];   // 10 KB (stride-13 pad)
    __shared__ float sHy[384];          // 3 edges x 128 cols
    __shared__ float sw6[768];          // w[3][128] then gg[3][128]
    __shared__ float smz[8];

    // ---- load compacted row list ----
    const int npad = npadArr[b];
    for (int i = t; i < npad; i += 384) scomp[i] = comp[(size_t)b * CMAX_ + i];
    __syncthreads();

    // ---- phase B: Hyper slice for cols n0..n0+127 (12 row-slices x 32 quads)
    const int cx = t & 31, ig = t >> 5;   // cx in [0,32), ig in [0,12)
    {
        float a0x=0,a0y=0,a0z=0,a0w=0, a1x=0,a1y=0,a1z=0,a1w=0, a2x=0,a2y=0,a2z=0,a2w=0;
        const float* bb = att + (size_t)b * N_ * N_ + n0 + cx * 4;
#pragma unroll 4
        for (int i = ig; i < npad; i += 12) {
            const float4 c = scomp[i];
            const f32x4 v = __builtin_nontemporal_load(
                (const f32x4*)(bb + (size_t)__float_as_int(c.x) * N_));
            a0x += c.y*v.x; a0y += c.y*v.y; a0z += c.y*v.z; a0w += c.y*v.w;
            a1x += c.z*v.x; a1y += c.z*v.y; a1z += c.z*v.z; a1w += c.z*v.w;
            a2x += c.w*v.x; a2y += c.w*v.y; a2z += c.w*v.z; a2w += c.w*v.w;
        }
        float a[12] = {a0x,a0y,a0z,a0w, a1x,a1y,a1z,a1w, a2x,a2y,a2z,a2w};
        // sum the 2 ig-slices in this wave (lane bit 5)
#pragma unroll
        for (int k = 0; k < 12; ++k) {
            float x = a[k];
            x += __shfl_xor(x, 32);
            a[k] = x;
        }
        if (lane < 32) {   // lane == cx for this wave's even slice
#pragma unroll
            for (int k = 0; k < 12; ++k) wred[wv][lane][k] = a[k];
        }
    }
    __syncthreads();
    {   // 32 col-quads x 12 components = 384 threads
        const int quad = t / 12, k = t % 12;
        float s = 0.f;
#pragma unroll
        for (int w2 = 0; w2 < 6; ++w2) s += wred[w2][quad][k];
        sHy[(k >> 2) * 128 + quad * 4 + (k & 3)] = s;
    }
    __syncthreads();

    // ---- local softmax stats over this chunk's 128 values (waves 0-2) ----
    if (wv < 3) {
        const float v0 = sHy[wv * 128 + lane];
        const float v1 = sHy[wv * 128 + 64 + lane];
        float m = fmaxf(v0, v1);
#pragma unroll
        for (int off = 32; off > 0; off >>= 1) m = fmaxf(m, __shfl_xor(m, off));
        float z = __expf(v0 - m) + __expf(v1 - m);
        z = wsum(z);
        if (lane == 0) { smz[wv] = m; smz[4 + wv] = z; }
    }
    __syncthreads();
    {   // 3 edges x 128 cols = 384 threads
        const int e = t >> 7, r2 = t & 127;
        const float Hv = sHy[e * 128 + r2];
        sw6[e * 128 + r2] = __expf(Hv - smz[e]);              // unnormalized
        sw6[384 + e * 128 + r2] = Hv * Dv[b * N_ + n0 + r2];
    }
    if (t < 3) {
        MZ[(size_t)(b * CH_ + chunk) * 8 + t]     = smz[t];
        MZ[(size_t)(b * CH_ + chunk) * 8 + 4 + t] = smz[4 + t];
    }
    __syncthreads();

    // ---- phase C: stream h rows n0..n0+127; 384 threads x float2 ----
    {
        float u00=0,u01=0, u10=0,u11=0, u20=0,u21=0;
        float g00=0,g01=0, g10=0,g11=0, g20=0,g21=0;
        const float* base = h + (size_t)b * N_ * H_ + (size_t)n0 * H_ + t * 2;
#pragma unroll 8
        for (int r2 = 0; r2 < 128; ++r2) {
            const f32x2 v = __builtin_nontemporal_load(
                (const f32x2*)(base + (size_t)r2 * H_));
            const float w0 = sw6[r2], w1 = sw6[128 + r2], w2 = sw6[256 + r2];
            const float g0 = sw6[384 + r2], g1 = sw6[512 + r2], g2 = sw6[640 + r2];
            u00 += w0*v.x; u01 += w0*v.y;
            u10 += w1*v.x; u11 += w1*v.y;
            u20 += w2*v.x; u21 += w2*v.y;
            g00 += g0*v.x; g01 += g0*v.y;
            g10 += g1*v.x; g11 += g1*v.y;
            g20 += g2*v.x; g21 += g2*v.y;
        }
        float* up = UGpart + (size_t)(b * CH_ + chunk) * 6 * H_ + t * 2;
        *(float2*)(up)          = make_float2(u00, u01);
        *(float2*)(up + H_)     = make_float2(u10, u11);
        *(float2*)(up + 2*H_)   = make_float2(u20, u21);
        *(float2*)(up + 3*H_)   = make_float2(g00, g01);
        *(float2*)(up + 4*H_)   = make_float2(g10, g11);
        *(float2*)(up + 5*H_)   = make_float2(g20, g21);
    }
}

// ---------------------------------------------------------------------------
// K45: combine online-softmax partials, then finalize.  grid=B, block=512.
// ---------------------------------------------------------------------------
#define K45T_ 512
__global__ __launch_bounds__(K45T_) void k45_fin(
    const float* __restrict__ UGpart, const float* __restrict__ MZ,
    const float* __restrict__ De, const float* __restrict__ Dv,
    const float* __restrict__ aind, const float* __restrict__ bind,
    const float* __restrict__ speak_all,
    const float* __restrict__ W_w, const float* __restrict__ W_b,
    const float* __restrict__ S_w, const float* __restrict__ S_b,
    float* __restrict__ out)
{
    const int b = blockIdx.x, tid = threadIdx.x;
    const int lane = tid & 63, wv = tid >> 6;   // 8 waves
    __shared__ float sUG[6 * H_];
    __shared__ float sKh[3 * H_];
    __shared__ float sscore[N_];
    __shared__ float sMZ[CH_ * 8];
    __shared__ float sscale[CH_ * 4];
    __shared__ float siZ[4];
    __shared__ float sred[24];
    __shared__ float sbest[8];
    __shared__ int sidx[8];

    if (tid < CH_ * 8) sMZ[tid] = MZ[(size_t)b * CH_ * 8 + tid];
    __syncthreads();
    if (tid < 3) {
        float m = -INFINITY;
        for (int c = 0; c < CH_; ++c) m = fmaxf(m, sMZ[c * 8 + tid]);
        float Z = 0.f;
        for (int c = 0; c < CH_; ++c) {
            const float sc = __expf(sMZ[c * 8 + tid] - m);
            sscale[c * 4 + tid] = sc;
            Z += sc * sMZ[c * 8 + 4 + tid];
        }
        siZ[tid] = 1.f / Z;
    }
    __syncthreads();

    // reduce 8 chunks: U scaled, G plain; 4-deep ILP
    {
        const float* p = UGpart + (size_t)b * CH_ * 6 * H_;
        for (int slot = tid; slot < 1152; slot += K45T_) {
            const int s = slot / 192;          // 0..5
            const int off = slot * 4;
            float4 a0 = make_float4(0,0,0,0), a1 = make_float4(0,0,0,0);
            float4 a2 = make_float4(0,0,0,0), a3 = make_float4(0,0,0,0);
            if (s < 3) {
#pragma unroll
                for (int c = 0; c < CH_; c += 4) {
                    const float w0 = sscale[(c+0) * 4 + s];
                    const float w1 = sscale[(c+1) * 4 + s];
                    const float w2 = sscale[(c+2) * 4 + s];
                    const float w3 = sscale[(c+3) * 4 + s];
                    const f32x4 v0 = __builtin_nontemporal_load((const f32x4*)(p + (size_t)(c+0) * 6 * H_ + off));
                    const f32x4 v1 = __builtin_nontemporal_load((const f32x4*)(p + (size_t)(c+1) * 6 * H_ + off));
                    const f32x4 v2 = __builtin_nontemporal_load((const f32x4*)(p + (size_t)(c+2) * 6 * H_ + off));
                    const f32x4 v3 = __builtin_nontemporal_load((const f32x4*)(p + (size_t)(c+3) * 6 * H_ + off));
                    a0.x += w0*v0.x; a0.y += w0*v0.y; a0.z += w0*v0.z; a0.w += w0*v0.w;
                    a1.x += w1*v1.x; a1.y += w1*v1.y; a1.z += w1*v1.z; a1.w += w1*v1.w;
                    a2.x += w2*v2.x; a2.y += w2*v2.y; a2.z += w2*v2.z; a2.w += w2*v2.w;
                    a3.x += w3*v3.x; a3.y += w3*v3.y; a3.z += w3*v3.z; a3.w += w3*v3.w;
                }
            } else {
#pragma unroll
                for (int c = 0; c < CH_; c += 4) {
                    const f32x4 v0 = __builtin_nontemporal_load((const f32x4*)(p + (size_t)(c+0) * 6 * H_ + off));
                    const f32x4 v1 = __builtin_nontemporal_load((const f32x4*)(p + (size_t)(c+1) * 6 * H_ + off));
                    const f32x4 v2 = __builtin_nontemporal_load((const f32x4*)(p + (size_t)(c+2) * 6 * H_ + off));
                    const f32x4 v3 = __builtin_nontemporal_load((const f32x4*)(p + (size_t)(c+3) * 6 * H_ + off));
                    a0.x += v0.x; a0.y += v0.y; a0.z += v0.z; a0.w += v0.w;
                    a1.x += v1.x; a1.y += v1.y; a1.z += v1.z; a1.w += v1.w;
                    a2.x += v2.x; a2.y += v2.y; a2.z += v2.z; a2.w += v2.w;
                    a3.x += v3.x; a3.y += v3.y; a3.z += v3.z; a3.w += v3.w;
                }
            }
            sUG[off + 0] = a0.x + a1.x + a2.x + a3.x;
            sUG[off + 1] = a0.y + a1.y + a2.y + a3.y;
            sUG[off + 2] = a0.z + a1.z + a2.z + a3.z;
            sUG[off + 3] = a0.w + a1.w + a2.w + a3.w;
        }
    }
    __syncthreads();

    const float* Ub = sUG;            // unnormalized exp-weighted sums
    const float* Gb = sUG + 3 * H_;   // exact

    float p0 = 0.f, p1 = 0.f, p2 = 0.f;
    for (int j = tid; j < H_; j += K45T_) {
        const float ww = W_w[j];
        p0 += Ub[j] * ww; p1 += Ub[H_ + j] * ww; p2 += Ub[2 * H_ + j] * ww;
    }
    p0 = wsum(p0); p1 = wsum(p1); p2 = wsum(p2);
    if (lane == 0) { sred[wv * 3 + 0] = p0; sred[wv * 3 + 1] = p1; sred[wv * 3 + 2] = p2; }
    __syncthreads();
    float l0 = 0.f, l1 = 0.f, l2 = 0.f;
    for (int k = 0; k < 8; ++k) { l0 += sred[k * 3]; l1 += sred[k * 3 + 1]; l2 += sred[k * 3 + 2]; }
    const float wb = W_b[0];
    l0 = l0 * siZ[0] + wb; l1 = l1 * siZ[1] + wb; l2 = l2 * siZ[2] + wb;
    const float mx = fmaxf(l0, fmaxf(l1, l2));
    const float e0 = expf(l0 - mx), e1 = expf(l1 - mx), e2 = expf(l2 - mx);
    const float inv = 1.f / (e0 + e1 + e2);
    const float wd0 = e0 * inv * De[b * 3 + 0];
    const float wd1 = e1 * inv * De[b * 3 + 1];
    const float wd2 = e2 * inv * De[b * 3 + 2];
    __syncthreads();

    for (int j = tid; j < H_; j += K45T_) {
        sKh[j]          = wd0 * Gb[j];
        sKh[H_ + j]     = wd1 * Gb[H_ + j];
        sKh[2 * H_ + j] = wd2 * Gb[2 * H_ + j];
    }
    __syncthreads();

    float q0 = 0.f, q1 = 0.f, q2 = 0.f;
    for (int j = tid; j < H_; j += K45T_) {
        const float sw2 = S_w[j];
        q0 += sKh[j] * sw2; q1 += sKh[H_ + j] * sw2; q2 += sKh[2 * H_ + j] * sw2;
    }
    q0 = wsum(q0); q1 = wsum(q1); q2 = wsum(q2);
    if (lane == 0) { sred[wv * 3 + 0] = q0; sred[wv * 3 + 1] = q1; sred[wv * 3 + 2] = q2; }
    __syncthreads();
    q0 = 0.f; q1 = 0.f; q2 = 0.f;
    for (int k = 0; k < 8; ++k) { q0 += sred[k * 3]; q1 += sred[k * 3 + 1]; q2 += sred[k * 3 + 2]; }

    const float sb0 = S_b[0];
    const float* av = aind + b * N_;
    const float* bv2 = bind + b * N_;
    const float* dv = Dv + b * N_;
    const float* sv = speak_all + (size_t)b * 3 * N_;
    for (int n = tid; n < N_; n += K45T_)
        sscore[n] = dv[n] * (av[n] * q0 + bv2[n] * q1 + sv[n] * q2) + sb0;
    __syncthreads();

    int r0;
    {
        float best = -INFINITY; int bi = N_;
        for (int n = tid; n < N_; n += K45T_) {
            const float s = sscore[n];
            if (s > best || (s == best && n < bi)) { best = s; bi = n; }
        }
#pragma unroll
        for (int off = 32; off > 0; off >>= 1) {
            const float ov = __shfl_xor(best, off); const int oi = __shfl_xor(bi, off);
            if (ov > best || (ov == best && oi < bi)) { best = ov; bi = oi; }
        }
        if (lane == 0) { sbest[wv] = best; sidx[wv] = bi; }
        __syncthreads();
        float v = -INFINITY; int i = N_;
        for (int k = 0; k < 8; ++k)
            if (sbest[k] > v || (sbest[k] == v && sidx[k] < i)) { v = sbest[k]; i = sidx[k]; }
        r0 = i;
    }
    __syncthreads();
    int r1;
    {
        float best = -INFINITY; int bi = N_;
        for (int n = tid; n < N_; n += K45T_) {
            if (n == r0) continue;
            const float s = sscore[n];
            if (s > best || (s == best && n < bi)) { best = s; bi = n; }
        }
#pragma unroll
        for (int off = 32; off > 0; off >>= 1) {
            const float ov = __shfl_xor(best, off); const int oi = __shfl_xor(bi, off);
            if (ov > best || (ov == best && oi < bi)) { best = ov; bi = oi; }
        }
        if (lane == 0) { sbest[wv] = best; sidx[wv] = bi; }
        __syncthreads();
        float v = -INFINITY; int i = N_;
        for (int k = 0; k < 8; ++k)
            if (sbest[k] > v || (sbest[k] == v && sidx[k] < i)) { v = sbest[k]; i = sidx[k]; }
        r1 = i;
    }

    float* ob = out + (size_t)b * 2 * H_;
    {
        const float d = dv[r0], wa = av[r0], wbn = bv2[r0], wsv = sv[r0];
        for (int j = tid; j < H_; j += K45T_)
            ob[j] = d * (wa * sKh[j] + wbn * sKh[H_ + j] + wsv * sKh[2 * H_ + j]);
    }
    {
        const float d = dv[r1], wa = av[r1], wbn = bv2[r1], wsv = sv[r1];
        for (int j = tid; j < H_; j += K45T_)
            ob[H_ + j] = d * (wa * sKh[j] + wbn * sKh[H_ + j] + wsv * sKh[2 * H_ + j]);
    }
}

extern "C" void kernel_launch(void* const* d_in, const int* in_sizes, int n_in,
                              void* d_out, int out_size, void* d_ws, size_t ws_size,
                              hipStream_t stream)
{
    const float* h         = (const float*)d_in[0];   // (B,N,H)
    const float* att       = (const float*)d_in[1];   // (B,1,N,N)
    const int*   a_idx     = (const int*)d_in[2];     // (B,8)
    const int*   b_idx     = (const int*)d_in[3];     // (B,8)
    const float* speak_all = (const float*)d_in[5];   // (B,3,N)
    const float* W_w       = (const float*)d_in[6];   // (1,H)
    const float* W_b       = (const float*)d_in[7];   // (1,)
    const float* S_w       = (const float*)d_in[8];   // (1,H)
    const float* S_b       = (const float*)d_in[9];   // (1,)
    float* out = (float*)d_out;

    float* ws      = (float*)d_ws;
    float* aind    = ws;                              // B*N
    float* bind    = aind + B_ * N_;                  // B*N
    float* Dv      = bind + B_ * N_;                  // B*N
    float* De      = Dv + B_ * N_;                    // 96, pad 128
    int*   npadArr = (int*)(De + 128);                // 32, pad 128
    float4* comp   = (float4*)(De + 256);             // B*CMAX_ float4
    float* MZ      = De + 256 + B_ * CMAX_ * 4;       // B*CH_*8
    float* UGpart  = MZ + B_ * CH_ * 8;               // B*CH_*6*H

    k1_ind<<<B_, 1024, 0, stream>>>(att, a_idx, b_idx, speak_all, aind, bind,
                                    Dv, De, comp, npadArr);
    kBC5<<<dim3(CH_, B_), 384, 0, stream>>>(att, comp, npadArr, h, Dv, UGpart, MZ);
    k45_fin<<<B_, K45T_, 0, stream>>>(UGpart, MZ, De, Dv, aind, bind, speak_all,
                                      W_w, W_b, S_w, S_b, out);
}